// Round 1
// baseline (2180.614 us; speedup 1.0000x reference)
//
#include <hip/hip_runtime.h>
#include <cstdint>
#include <cstddef>

#define Bb 2
#define Ss 1024
#define Dd 768
#define Hh 8
#define HDh 96
#define Mm 3072
#define Vv 32000
#define KVr 2049   // 2S+1

typedef __attribute__((ext_vector_type(8))) short short8v;
typedef __attribute__((ext_vector_type(4))) short short4v;
typedef __attribute__((ext_vector_type(4))) float f32x4;

static __device__ __forceinline__ short f2bf(float f) {
  union { float f; unsigned u; } x; x.f = f;
  unsigned r = (x.u + 0x7FFFu + ((x.u >> 16) & 1u)) >> 16;  // RNE
  return (short)(r & 0xFFFFu);
}

static __device__ __forceinline__ float gelu_tanh(float v) {
  float t = tanhf(0.7978845608028654f * (v + 0.044715f * v * v * v));
  return 0.5f * v * (1.0f + t);
}

static __device__ __forceinline__ float blk_sum(float val, float* sh) {
  #pragma unroll
  for (int off = 32; off >= 1; off >>= 1) val += __shfl_xor(val, off);
  __syncthreads();
  if ((threadIdx.x & 63) == 0) sh[threadIdx.x >> 6] = val;
  __syncthreads();
  return sh[0] + sh[1] + sh[2] + sh[3];
}

// ---------------- prep: inputs, LN(l2r), LN(r2l), qin, all_e rows ----------------
__global__ __launch_bounds__(256) void prep_kernel(
    const float* __restrict__ l2r, const float* __restrict__ r2l,
    const float* __restrict__ s1, const float* __restrict__ b1,
    const float* __restrict__ s2, const float* __restrict__ b2,
    float* __restrict__ inputs, float* __restrict__ qin, float* __restrict__ all_e)
{
  __shared__ float sh[4];
  const int row = blockIdx.x, tid = threadIdx.x;
  const int b = row >> 10, s = row & 1023;
  const float* ap = l2r + (size_t)row * Dd;
  const float* cp = r2l + (size_t)row * Dd;
  float a0 = ap[tid], a1 = ap[tid + 256], a2 = ap[tid + 512];
  float c0 = cp[tid], c1 = cp[tid + 256], c2 = cp[tid + 512];
  float ma = blk_sum(a0 + a1 + a2, sh) * (1.f / 768.f);
  float mc = blk_sum(c0 + c1 + c2, sh) * (1.f / 768.f);
  float va = blk_sum((a0-ma)*(a0-ma) + (a1-ma)*(a1-ma) + (a2-ma)*(a2-ma), sh) * (1.f / 768.f);
  float vc = blk_sum((c0-mc)*(c0-mc) + (c1-mc)*(c1-mc) + (c2-mc)*(c2-mc), sh) * (1.f / 768.f);
  float ia = rsqrtf(va + 1e-6f), ic = rsqrtf(vc + 1e-6f);
  size_t ro = (size_t)row * Dd;
  size_t e1 = ((size_t)b * KVr + 1 + s) * Dd;
  size_t e2 = ((size_t)b * KVr + 1 + Ss + s) * Dd;
  float av[3] = {a0, a1, a2}, cv[3] = {c0, c1, c2};
  #pragma unroll
  for (int i = 0; i < 3; ++i) {
    int c = tid + i * 256;
    float an = (av[i] - ma) * ia * s1[c] + b1[c];
    float cn = (cv[i] - mc) * ic * s2[c] + b2[c];
    inputs[ro + c] = av[i] + cv[i];
    qin[ro + c]    = an + cn;
    all_e[e1 + c]  = an;
    all_e[e2 + c]  = cn;
  }
}

__global__ __launch_bounds__(256) void temb_copy(const float* __restrict__ temb,
                                                 float* __restrict__ all_e)
{
  int b = blockIdx.x, tid = threadIdx.x;
  #pragma unroll
  for (int i = 0; i < 3; ++i)
    all_e[(size_t)b * KVr * Dd + tid + i * 256] = temb[(size_t)b * Dd + tid + i * 256];
}

// ---------------- LayerNorm (+optional FiLM) ----------------
__global__ __launch_bounds__(256) void ln_kernel(
    const float* __restrict__ x, const float* __restrict__ sc, const float* __restrict__ bi,
    const float* __restrict__ film, float* __restrict__ y)
{
  __shared__ float sh[4];
  const int row = blockIdx.x, tid = threadIdx.x;
  const float* xr = x + (size_t)row * Dd;
  float v0 = xr[tid], v1 = xr[tid + 256], v2 = xr[tid + 512];
  float m = blk_sum(v0 + v1 + v2, sh) * (1.f / 768.f);
  float var = blk_sum((v0-m)*(v0-m) + (v1-m)*(v1-m) + (v2-m)*(v2-m), sh) * (1.f / 768.f);
  float inv = rsqrtf(var + 1e-6f);
  int bb = row >> 10;
  float vv[3] = {v0, v1, v2};
  #pragma unroll
  for (int i = 0; i < 3; ++i) {
    int c = tid + i * 256;
    float o = (vv[i] - m) * inv * sc[c] + bi[c];
    if (film) o = film[(size_t)bb * 1536 + c] * o + film[(size_t)bb * 1536 + 768 + c];
    y[(size_t)row * Dd + c] = o;
  }
}

// ---------------- generic 128x128 bf16-MFMA GEMM, f32 in/out ----------------
// C[M,N] = act((A[M,K] @ W[K,N] + bias)*scale) (+ res)
template<int ACT, int RES>
__global__ __launch_bounds__(256) void gemm128(
    const float* __restrict__ A, const float* __restrict__ W,
    const float* __restrict__ bias, const float* __restrict__ res,
    float* __restrict__ C, int M, int N, int K, float scale, int ntiles)
{
  __shared__ short As[128][40];   // [m][k] bf16, +8 pad
  __shared__ short Bs[128][40];   // [n][k] bf16 (transposed W tile), +8 pad
  const int tid = threadIdx.x;
  const int lane = tid & 63, wv = tid >> 6;
  const int l15 = lane & 15, l4 = lane >> 4;
  const int bx = blockIdx.x % ntiles, by = blockIdx.x / ntiles;
  const int m0 = by * 128, n0 = bx * 128;
  const int wm = (wv >> 1) * 64, wn = (wv & 1) * 64;

  f32x4 acc[4][4];
  const f32x4 zz = {0.f, 0.f, 0.f, 0.f};
  #pragma unroll
  for (int i = 0; i < 4; ++i)
    #pragma unroll
    for (int j = 0; j < 4; ++j) acc[i][j] = zz;

  for (int k0 = 0; k0 < K; k0 += 32) {
    __syncthreads();
    // stage A [128 m][32 k]: coalesced float4 rows, linear LDS writes
    #pragma unroll
    for (int i = 0; i < 4; ++i) {
      int f = i * 256 + tid;
      int r = f >> 3, c = (f & 7) * 4;
      float4 a4 = make_float4(0.f, 0.f, 0.f, 0.f);
      int row = m0 + r;
      if (row < M) a4 = *(const float4*)(A + (size_t)row * K + k0 + c);
      short4v s4 = { f2bf(a4.x), f2bf(a4.y), f2bf(a4.z), f2bf(a4.w) };
      *(short4v*)&As[r][c] = s4;
    }
    // stage W tile transposed into Bs[n][k]: k-per-lane global (L1-buffered), contiguous LDS writes
    #pragma unroll
    for (int i = 0; i < 4; ++i) {
      int f = i * 256 + tid;
      int kr = f & 31;
      int nc = (f >> 5) * 4;
      float4 b4 = *(const float4*)(W + (size_t)(k0 + kr) * N + n0 + nc);
      Bs[nc + 0][kr] = f2bf(b4.x);
      Bs[nc + 1][kr] = f2bf(b4.y);
      Bs[nc + 2][kr] = f2bf(b4.z);
      Bs[nc + 3][kr] = f2bf(b4.w);
    }
    __syncthreads();
    short8v af[4], bf[4];
    #pragma unroll
    for (int mi = 0; mi < 4; ++mi) af[mi] = *(const short8v*)&As[wm + mi * 16 + l15][l4 * 8];
    #pragma unroll
    for (int ni = 0; ni < 4; ++ni) bf[ni] = *(const short8v*)&Bs[wn + ni * 16 + l15][l4 * 8];
    #pragma unroll
    for (int mi = 0; mi < 4; ++mi)
      #pragma unroll
      for (int ni = 0; ni < 4; ++ni)
        acc[mi][ni] = __builtin_amdgcn_mfma_f32_16x16x32_bf16(af[mi], bf[ni], acc[mi][ni], 0, 0, 0);
  }
  // epilogue: D row=(lane>>4)*4+r, col=lane&15
  #pragma unroll
  for (int mi = 0; mi < 4; ++mi) {
    #pragma unroll
    for (int r = 0; r < 4; ++r) {
      int row = m0 + wm + mi * 16 + l4 * 4 + r;
      if (row >= M) continue;
      #pragma unroll
      for (int ni = 0; ni < 4; ++ni) {
        int col = n0 + wn + ni * 16 + l15;
        float val = (acc[mi][ni][r] + bias[col]) * scale;
        if (ACT == 1) val = fmaxf(val, 0.f);
        if (ACT == 2) val = gelu_tanh(val);
        if (RES) val += res[(size_t)row * N + col];
        C[(size_t)row * N + col] = val;
      }
    }
  }
}

// ---------------- flash attention with dual-causal mask ----------------
// q:[B*S,768] (pre-scaled), k,v:[B*2049,768], o:[B*S,768] (col = h*96+hd)
__global__ __launch_bounds__(256) void attn_kernel(
    const float* __restrict__ q, const float* __restrict__ k, const float* __restrict__ v,
    float* __restrict__ o)
{
  __shared__ short Kls[64][104];     // [key][feat] bf16, +8 pad
  __shared__ short Vt[96][72];       // [feat][key] bf16, +8 pad
  __shared__ short Pls[4][16][72];   // per-wave P [q][key]

  const int tid = threadIdx.x, lane = tid & 63, w = tid >> 6;
  const int l15 = lane & 15, l4 = lane >> 4;
  const int qt = blockIdx.x & 15;
  const int bh = blockIdx.x >> 4;
  const int h = bh & 7, b = bh >> 3;
  const int qb = qt * 64;
  const int qw = qb + w * 16;

  // Q fragments (3 k-steps of 32 over HD=96)
  short8v qf[3];
  {
    const float* qp = q + ((size_t)(b * Ss + qw + l15)) * Dd + h * HDh + l4 * 8;
    #pragma unroll
    for (int kk = 0; kk < 3; ++kk) {
      float4 x0 = *(const float4*)(qp + kk * 32);
      float4 x1 = *(const float4*)(qp + kk * 32 + 4);
      short8v tq;
      tq[0] = f2bf(x0.x); tq[1] = f2bf(x0.y); tq[2] = f2bf(x0.z); tq[3] = f2bf(x0.w);
      tq[4] = f2bf(x1.x); tq[5] = f2bf(x1.y); tq[6] = f2bf(x1.z); tq[7] = f2bf(x1.w);
      qf[kk] = tq;
    }
  }

  const f32x4 zz = {0.f, 0.f, 0.f, 0.f};
  f32x4 Oa[6];
  #pragma unroll
  for (int fn = 0; fn < 6; ++fn) Oa[fn] = zz;
  float mrow[4], lrow[4];
  #pragma unroll
  for (int r = 0; r < 4; ++r) { mrow[r] = -3.0e38f; lrow[r] = 0.f; }

  const size_t kvbase = (size_t)b * KVr;

  for (int t = 0; t < 33; ++t) {
    int k0 = t * 64;
    bool l2r_vis = (k0 <= Ss) && (k0 - 1 <= qb + 63);
    int rmaxk = (k0 + 63 > 2 * Ss) ? 2 * Ss : (k0 + 63);
    bool r2l_vis = (k0 + 63 >= Ss + 1) && (rmaxk - (Ss + 1) >= qb);
    if (!(t == 0 || l2r_vis || r2l_vis)) continue;

    __syncthreads();
    #pragma unroll
    for (int i = 0; i < 6; ++i) {
      int f = i * 256 + tid;
      { // K tile: [64 key][96 feat]
        int row = f / 24, cq = (f % 24) * 4;
        int key = k0 + row;
        float4 k4 = make_float4(0.f, 0.f, 0.f, 0.f);
        if (key <= 2 * Ss) k4 = *(const float4*)(k + (kvbase + key) * Dd + h * HDh + cq);
        short4v ks = { f2bf(k4.x), f2bf(k4.y), f2bf(k4.z), f2bf(k4.w) };
        *(short4v*)&Kls[row][cq] = ks;
      }
      { // V tile transposed: key-per-lane, contiguous LDS writes
        int key = k0 + (f & 63);
        int fq = (f >> 6) * 4;
        float4 v4 = make_float4(0.f, 0.f, 0.f, 0.f);
        if (key <= 2 * Ss) v4 = *(const float4*)(v + (kvbase + key) * Dd + h * HDh + fq);
        Vt[fq + 0][f & 63] = f2bf(v4.x);
        Vt[fq + 1][f & 63] = f2bf(v4.y);
        Vt[fq + 2][f & 63] = f2bf(v4.z);
        Vt[fq + 3][f & 63] = f2bf(v4.w);
      }
    }
    __syncthreads();

    // scores: 4 n-subtiles x (K=96 in 3 steps)
    f32x4 sc[4];
    #pragma unroll
    for (int nt = 0; nt < 4; ++nt) {
      f32x4 d = zz;
      #pragma unroll
      for (int kk = 0; kk < 3; ++kk) {
        short8v kf = *(const short8v*)&Kls[nt * 16 + l15][kk * 32 + l4 * 8];
        d = __builtin_amdgcn_mfma_f32_16x16x32_bf16(qf[kk], kf, d, 0, 0, 0);
      }
      sc[nt] = d;
    }
    // mask + running max
    float tmax[4] = {-3.0e38f, -3.0e38f, -3.0e38f, -3.0e38f};
    #pragma unroll
    for (int nt = 0; nt < 4; ++nt)
      #pragma unroll
      for (int r = 0; r < 4; ++r) {
        int qg = qw + l4 * 4 + r;
        int j = k0 + nt * 16 + l15;
        bool vis = (j == 0) ||
                   (j >= 1 && j <= Ss && (j - 1) <= qg) ||
                   (j >= Ss + 1 && j <= 2 * Ss && (j - (Ss + 1)) >= qg);
        if (!vis) sc[nt][r] = -3.0e38f;
        tmax[r] = fmaxf(tmax[r], sc[nt][r]);
      }
    #pragma unroll
    for (int r = 0; r < 4; ++r) {
      #pragma unroll
      for (int off = 8; off >= 1; off >>= 1) tmax[r] = fmaxf(tmax[r], __shfl_xor(tmax[r], off));
    }
    float scl[4];
    #pragma unroll
    for (int r = 0; r < 4; ++r) {
      float mnew = fmaxf(mrow[r], tmax[r]);
      scl[r] = __expf(mrow[r] - mnew);
      mrow[r] = mnew;
    }
    #pragma unroll
    for (int fn = 0; fn < 6; ++fn)
      #pragma unroll
      for (int r = 0; r < 4; ++r) Oa[fn][r] *= scl[r];
    float lad[4] = {0.f, 0.f, 0.f, 0.f};
    #pragma unroll
    for (int nt = 0; nt < 4; ++nt)
      #pragma unroll
      for (int r = 0; r < 4; ++r) {
        float p = __expf(sc[nt][r] - mrow[r]);
        lad[r] += p;
        Pls[w][l4 * 4 + r][nt * 16 + l15] = f2bf(p);
      }
    #pragma unroll
    for (int r = 0; r < 4; ++r) {
      #pragma unroll
      for (int off = 8; off >= 1; off >>= 1) lad[r] += __shfl_xor(lad[r], off);
      lrow[r] = lrow[r] * scl[r] + lad[r];
    }
    __syncthreads();   // P writes visible wave-wide (and block lockstep)

    // PV: O[16q x 96f] += P[16q x 64k] @ V[64k x 96f]
    short8v pf[2];
    #pragma unroll
    for (int kk = 0; kk < 2; ++kk) pf[kk] = *(const short8v*)&Pls[w][l15][kk * 32 + l4 * 8];
    #pragma unroll
    for (int fn = 0; fn < 6; ++fn) {
      #pragma unroll
      for (int kk = 0; kk < 2; ++kk) {
        short8v vf = *(const short8v*)&Vt[fn * 16 + l15][kk * 32 + l4 * 8];
        Oa[fn] = __builtin_amdgcn_mfma_f32_16x16x32_bf16(pf[kk], vf, Oa[fn], 0, 0, 0);
      }
    }
  }

  #pragma unroll
  for (int fn = 0; fn < 6; ++fn)
    #pragma unroll
    for (int r = 0; r < 4; ++r) {
      int row = qw + l4 * 4 + r;
      int col = h * HDh + fn * 16 + l15;
      o[((size_t)(b * Ss + row)) * Dd + col] = Oa[fn][r] / lrow[r];
    }
}

// ---------------- launcher ----------------
static void launch_gemm(int act, int res, const float* A, const float* W, const float* bias,
                        const float* rsd, float* C, int M, int N, int K, float scale,
                        hipStream_t stream)
{
  int mt = (M + 127) >> 7, nt = N >> 7;
  dim3 grid(mt * nt), blk(256);
  if (res)           gemm128<0, 1><<<grid, blk, 0, stream>>>(A, W, bias, rsd, C, M, N, K, scale, nt);
  else if (act == 1) gemm128<1, 0><<<grid, blk, 0, stream>>>(A, W, bias, nullptr, C, M, N, K, scale, nt);
  else if (act == 2) gemm128<2, 0><<<grid, blk, 0, stream>>>(A, W, bias, nullptr, C, M, N, K, scale, nt);
  else               gemm128<0, 0><<<grid, blk, 0, stream>>>(A, W, bias, nullptr, C, M, N, K, scale, nt);
}

extern "C" void kernel_launch(void* const* d_in, const int* in_sizes, int n_in,
                              void* d_out, int out_size, void* d_ws, size_t ws_size,
                              hipStream_t stream)
{
  (void)in_sizes; (void)n_in; (void)out_size; (void)ws_size;
  const float* l2r      = (const float*)d_in[0];
  const float* r2l      = (const float*)d_in[1];
  const float* temb     = (const float*)d_in[2];
  const float* ln_l2r_s = (const float*)d_in[3];
  const float* ln_l2r_b = (const float*)d_in[4];
  const float* ln_r2l_s = (const float*)d_in[5];
  const float* ln_r2l_b = (const float*)d_in[6];
  const float* Wq = (const float*)d_in[7];
  const float* bq = (const float*)d_in[8];
  const float* Wk = (const float*)d_in[9];
  const float* bk = (const float*)d_in[10];
  const float* Wv = (const float*)d_in[11];
  const float* bv = (const float*)d_in[12];
  const float* Wo = (const float*)d_in[13];
  const float* bo = (const float*)d_in[14];
  const float* ff_ln_s = (const float*)d_in[15];
  const float* ff_ln_b = (const float*)d_in[16];
  const float* ff_w1 = (const float*)d_in[17];
  const float* ff_b1 = (const float*)d_in[18];
  const float* ff_w2 = (const float*)d_in[19];
  const float* ff_b2 = (const float*)d_in[20];
  const float* tm_w1 = (const float*)d_in[21];
  const float* tm_b1 = (const float*)d_in[22];
  const float* tm_w2 = (const float*)d_in[23];
  const float* tm_b2 = (const float*)d_in[24];
  const float* film_w = (const float*)d_in[25];
  const float* film_b = (const float*)d_in[26];
  const float* r_w1 = (const float*)d_in[27];
  const float* r_b1 = (const float*)d_in[28];
  const float* r_w2 = (const float*)d_in[29];
  const float* r_b2 = (const float*)d_in[30];
  const float* r_ln_s = (const float*)d_in[31];
  const float* r_ln_b = (const float*)d_in[32];
  const float* out_w = (const float*)d_in[33];
  const float* out_b = (const float*)d_in[34];

  float* ws = (float*)d_ws;
  const size_t R1 = (size_t)2048 * 768;     // 1,572,864
  const size_t AE = (size_t)4098 * 768;     // 3,147,264
  float* inputs = ws;                 // later: x2
  float* qin    = ws + R1;            // later: attn out
  float* qbuf   = ws + 2 * R1;        // later: x3
  float* all_e  = ws + 3 * R1;        // later: xn (at 3R1)
  float* xn     = ws + 3 * R1;
  float* xbuf   = ws + 4 * R1;        // x after Wo+res; later: u
  float* kbuf   = ws + 3 * R1 + AE;   // later: u2
  float* vbuf   = ws + 3 * R1 + 2 * AE; // later: x4
  float* big    = ws + 3 * R1 + 3 * AE; // [2048,3072]
  float* t1     = big + (size_t)2048 * 3072;
  float* tb     = t1 + 8192;
  float* f0     = tb + 8192;
  float* f1     = f0 + 4096;
  float* attn   = qin;
  float* x2     = inputs;
  float* u      = xbuf;
  float* x3     = qbuf;
  float* u2     = kbuf;
  float* x4     = vbuf;

  dim3 blk(256);
  const float qscale = 0.1020620726159658f;  // 1/sqrt(96)

  prep_kernel<<<2048, blk, 0, stream>>>(l2r, r2l, ln_l2r_s, ln_l2r_b, ln_r2l_s, ln_r2l_b,
                                        inputs, qin, all_e);
  temb_copy<<<2, blk, 0, stream>>>(temb, all_e);

  launch_gemm(0, 0, qin,   Wq, bq, nullptr, qbuf, 2048, 768, 768, qscale, stream);
  launch_gemm(0, 0, all_e, Wk, bk, nullptr, kbuf, 4098, 768, 768, 1.f, stream);
  launch_gemm(0, 0, all_e, Wv, bv, nullptr, vbuf, 4098, 768, 768, 1.f, stream);

  attn_kernel<<<256, blk, 0, stream>>>(qbuf, kbuf, vbuf, attn);

  launch_gemm(0, 1, attn, Wo, bo, inputs, xbuf, 2048, 768, 768, 1.f, stream);
  ln_kernel<<<2048, blk, 0, stream>>>(xbuf, ff_ln_s, ff_ln_b, nullptr, xn);
  launch_gemm(1, 0, xn,  ff_w1, ff_b1, nullptr, big, 2048, 3072, 768, 1.f, stream);
  launch_gemm(0, 1, big, ff_w2, ff_b2, xbuf,   x2,  2048, 768, 3072, 1.f, stream);

  // FiLM conditioning path (M=2)
  launch_gemm(2, 0, temb, tm_w1, tm_b1, nullptr, t1, 2, 3072, 768,  1.f, stream);
  launch_gemm(0, 0, t1,   tm_w2, tm_b2, nullptr, tb, 2, 3072, 3072, 1.f, stream);
  launch_gemm(0, 0, tb, film_w,                       film_b,        nullptr, f0, 2, 1536, 3072, 1.f, stream);
  launch_gemm(0, 0, tb, film_w + (size_t)3072 * 1536, film_b + 1536, nullptr, f1, 2, 1536, 3072, 1.f, stream);

  // residual block 0
  launch_gemm(2, 0, x2,  r_w1, r_b1, nullptr, big, 2048, 3072, 768, 1.f, stream);
  launch_gemm(0, 1, big, r_w2, r_b2, x2,      u,   2048, 768, 3072, 1.f, stream);
  ln_kernel<<<2048, blk, 0, stream>>>(u, r_ln_s, r_ln_b, f0, x3);
  // residual block 1
  launch_gemm(2, 0, x3,  r_w1 + (size_t)768 * 3072, r_b1 + 3072, nullptr, big, 2048, 3072, 768, 1.f, stream);
  launch_gemm(0, 1, big, r_w2 + (size_t)3072 * 768, r_b2 + 768,  x3,      u2,  2048, 768, 3072, 1.f, stream);
  ln_kernel<<<2048, blk, 0, stream>>>(u2, r_ln_s + 768, r_ln_b + 768, f1, x4);

  // vocab projection
  launch_gemm(0, 0, x4, out_w, out_b, nullptr, (float*)d_out, 2048, 32000, 768, 1.f, stream);
}

// Round 2
// 894.416 us; speedup vs baseline: 2.4380x; 2.4380x over previous
//
#include <hip/hip_runtime.h>
#include <cstdint>
#include <cstddef>

#define Bb 2
#define Ss 1024
#define Dd 768
#define Hh 8
#define HDh 96
#define Mm 3072
#define Vv 32000
#define KVr 2049   // 2S+1

typedef __attribute__((ext_vector_type(8))) short short8v;
typedef __attribute__((ext_vector_type(4))) short short4v;
typedef __attribute__((ext_vector_type(4))) float f32x4;

#define GL16(gp, lp) __builtin_amdgcn_global_load_lds( \
    (const __attribute__((address_space(1))) void*)(gp), \
    (__attribute__((address_space(3))) void*)(lp), 16, 0, 0)

static __device__ __forceinline__ short f2bf(float f) {
  union { float f; unsigned u; } x; x.f = f;
  unsigned r = (x.u + 0x7FFFu + ((x.u >> 16) & 1u)) >> 16;  // RNE
  return (short)(r & 0xFFFFu);
}

static __device__ __forceinline__ float gelu_f(float v) {
  float u = 0.7978845608028654f * (v + 0.044715f * v * v * v);
  float au = fabsf(u);
  float e = __expf(2.f * au);
  float t = 1.f - 2.f / (e + 1.f);     // tanh(|u|), safe at inf
  return 0.5f * v * (1.f + copysignf(t, u));
}

static __device__ __forceinline__ float blk_sum(float val, float* sh) {
  #pragma unroll
  for (int off = 32; off >= 1; off >>= 1) val += __shfl_xor(val, off);
  __syncthreads();
  if ((threadIdx.x & 63) == 0) sh[threadIdx.x >> 6] = val;
  __syncthreads();
  return sh[0] + sh[1] + sh[2] + sh[3];
}

// ---------------- prep: inputs(f32), qin(bf16), all_e rows (bf16) ----------------
__global__ __launch_bounds__(256) void prep_kernel(
    const float* __restrict__ l2r, const float* __restrict__ r2l,
    const float* __restrict__ s1, const float* __restrict__ b1,
    const float* __restrict__ s2, const float* __restrict__ b2,
    float* __restrict__ inputs, short* __restrict__ qin, short* __restrict__ all_e)
{
  __shared__ float sh[4];
  const int row = blockIdx.x, tid = threadIdx.x;
  const int b = row >> 10, s = row & 1023;
  const float* ap = l2r + (size_t)row * Dd;
  const float* cp = r2l + (size_t)row * Dd;
  float a0 = ap[tid], a1 = ap[tid + 256], a2 = ap[tid + 512];
  float c0 = cp[tid], c1 = cp[tid + 256], c2 = cp[tid + 512];
  float ma = blk_sum(a0 + a1 + a2, sh) * (1.f / 768.f);
  float mc = blk_sum(c0 + c1 + c2, sh) * (1.f / 768.f);
  float va = blk_sum((a0-ma)*(a0-ma) + (a1-ma)*(a1-ma) + (a2-ma)*(a2-ma), sh) * (1.f / 768.f);
  float vc = blk_sum((c0-mc)*(c0-mc) + (c1-mc)*(c1-mc) + (c2-mc)*(c2-mc), sh) * (1.f / 768.f);
  float ia = rsqrtf(va + 1e-6f), ic = rsqrtf(vc + 1e-6f);
  size_t ro = (size_t)row * Dd;
  size_t e1 = ((size_t)b * KVr + 1 + s) * Dd;
  size_t e2 = ((size_t)b * KVr + 1 + Ss + s) * Dd;
  float av[3] = {a0, a1, a2}, cv[3] = {c0, c1, c2};
  #pragma unroll
  for (int i = 0; i < 3; ++i) {
    int c = tid + i * 256;
    float an = (av[i] - ma) * ia * s1[c] + b1[c];
    float cn = (cv[i] - mc) * ic * s2[c] + b2[c];
    inputs[ro + c] = av[i] + cv[i];
    qin[ro + c]    = f2bf(an + cn);
    all_e[e1 + c]  = f2bf(an);
    all_e[e2 + c]  = f2bf(cn);
  }
}

__global__ __launch_bounds__(256) void temb_cvt(const float* __restrict__ temb,
                                                short* __restrict__ all_e)
{
  int b = blockIdx.x, tid = threadIdx.x;
  #pragma unroll
  for (int i = 0; i < 3; ++i)
    all_e[(size_t)b * KVr * Dd + tid + i * 256] = f2bf(temb[(size_t)b * Dd + tid + i * 256]);
}

// ---------------- LayerNorm (+optional FiLM); f32 and/or bf16 out ----------------
__global__ __launch_bounds__(256) void ln_kernel(
    const float* __restrict__ x, const float* __restrict__ sc, const float* __restrict__ bi,
    const float* __restrict__ film, float* __restrict__ yf, short* __restrict__ yb)
{
  __shared__ float sh[4];
  const int row = blockIdx.x, tid = threadIdx.x;
  const float* xr = x + (size_t)row * Dd;
  float v0 = xr[tid], v1 = xr[tid + 256], v2 = xr[tid + 512];
  float m = blk_sum(v0 + v1 + v2, sh) * (1.f / 768.f);
  float var = blk_sum((v0-m)*(v0-m) + (v1-m)*(v1-m) + (v2-m)*(v2-m), sh) * (1.f / 768.f);
  float inv = rsqrtf(var + 1e-6f);
  int bb = row >> 10;
  float vv[3] = {v0, v1, v2};
  #pragma unroll
  for (int i = 0; i < 3; ++i) {
    int c = tid + i * 256;
    float o = (vv[i] - m) * inv * sc[c] + bi[c];
    if (film) o = film[(size_t)bb * 1536 + c] * o + film[(size_t)bb * 1536 + 768 + c];
    if (yf) yf[(size_t)row * Dd + c] = o;
    if (yb) yb[(size_t)row * Dd + c] = f2bf(o);
  }
}

// ---------------- weight convert+transpose: f32 [K][N] -> bf16 [N][K] ----------------
__global__ __launch_bounds__(256) void convT(const float* __restrict__ W, short* __restrict__ Wt,
                                             int K, int N, int ntile)
{
  __shared__ short T[64][72];
  const int bn = blockIdx.x % ntile, bk = blockIdx.x / ntile;
  const int k0 = bk * 64, n0 = bn * 64, tid = threadIdx.x;
  #pragma unroll
  for (int i = 0; i < 4; ++i) {
    int id = i * 256 + tid;
    int r = id >> 4, c4 = (id & 15) * 4;
    float4 w4 = *(const float4*)(W + (size_t)(k0 + r) * N + n0 + c4);
    T[c4 + 0][r] = f2bf(w4.x);
    T[c4 + 1][r] = f2bf(w4.y);
    T[c4 + 2][r] = f2bf(w4.z);
    T[c4 + 3][r] = f2bf(w4.w);
  }
  __syncthreads();
  #pragma unroll
  for (int i = 0; i < 4; ++i) {
    int id = i * 256 + tid;
    int n = id >> 4, k4 = (id & 15) * 4;
    short4v s = *(const short4v*)&T[n][k4];
    *(short4v*)(Wt + (size_t)(n0 + n) * K + k0 + k4) = s;
  }
}

__global__ __launch_bounds__(256) void kvbias_kernel(const float* __restrict__ bk,
                                                     const float* __restrict__ bv,
                                                     float* __restrict__ kvb)
{
  int i = blockIdx.x * 256 + threadIdx.x;
  if (i < 1536) kvb[i] = (i < 768) ? bk[i] : bv[i - 768];
}

// ---------------- bf16 MFMA GEMM: A[M][K] bf16, Bt[N][K] bf16 ----------------
// C = act((A@Bt^T + bias)*scale) (+res). BK=64, global_load_lds, XOR-swizzled chunks.
template<int ACT>
__global__ __launch_bounds__(256) void gemm_bf(
    const short* __restrict__ A, const short* __restrict__ Bt,
    const float* __restrict__ bias, const float* __restrict__ res,
    float* __restrict__ C, short* __restrict__ Cbf,
    int M, int N, int K, float scale, int mtiles)
{
  __shared__ short As[8192];   // [128][64] linear, content chunk-swizzled
  __shared__ short Bs[8192];
  const int tid = threadIdx.x, lane = tid & 63, wv = tid >> 6;
  const int l15 = lane & 15, l4 = lane >> 4;
  const int by = blockIdx.x % mtiles, bx = blockIdx.x / mtiles;
  const int m0 = by * 128, n0 = bx * 128;
  const int wm = (wv >> 1) * 64, wn = (wv & 1) * 64;
  const int r8 = lane >> 3, c8 = lane & 7;
  const int csw = ((c8 ^ r8) << 3);   // pre-swizzled source chunk offset (shorts)

  f32x4 acc[4][4];
  const f32x4 zz = {0.f, 0.f, 0.f, 0.f};
  #pragma unroll
  for (int i = 0; i < 4; ++i)
    #pragma unroll
    for (int j = 0; j < 4; ++j) acc[i][j] = zz;

  const short* Ab = A + (size_t)m0 * K + csw;
  const short* Bp = Bt + (size_t)n0 * K + csw;

  for (int k0 = 0; k0 < K; k0 += 64) {
    __syncthreads();
    #pragma unroll
    for (int i = 0; i < 4; ++i) {
      int row = wv * 32 + i * 8 + r8;
      GL16(Ab + (size_t)row * K + k0, &As[(wv * 4 + i) * 512]);
      GL16(Bp + (size_t)row * K + k0, &Bs[(wv * 4 + i) * 512]);
    }
    __syncthreads();
    short8v af[2][4], bfv[2][4];
    #pragma unroll
    for (int kk = 0; kk < 2; ++kk) {
      #pragma unroll
      for (int mi = 0; mi < 4; ++mi)
        af[kk][mi] = *(const short8v*)&As[(wm + mi * 16 + l15) * 64 + ((((kk << 2) | l4) ^ (l15 & 7)) << 3)];
      #pragma unroll
      for (int ni = 0; ni < 4; ++ni)
        bfv[kk][ni] = *(const short8v*)&Bs[(wn + ni * 16 + l15) * 64 + ((((kk << 2) | l4) ^ (l15 & 7)) << 3)];
    }
    #pragma unroll
    for (int kk = 0; kk < 2; ++kk)
      #pragma unroll
      for (int mi = 0; mi < 4; ++mi)
        #pragma unroll
        for (int ni = 0; ni < 4; ++ni)
          acc[mi][ni] = __builtin_amdgcn_mfma_f32_16x16x32_bf16(af[kk][mi], bfv[kk][ni], acc[mi][ni], 0, 0, 0);
  }

  #pragma unroll
  for (int mi = 0; mi < 4; ++mi) {
    #pragma unroll
    for (int r = 0; r < 4; ++r) {
      int row = m0 + wm + mi * 16 + l4 * 4 + r;
      if (row >= M) continue;
      size_t rb = (size_t)row * N;
      #pragma unroll
      for (int ni = 0; ni < 4; ++ni) {
        int col = n0 + wn + ni * 16 + l15;
        float val = (acc[mi][ni][r] + bias[col]) * scale;
        if (ACT == 1) val = fmaxf(val, 0.f);
        if (ACT == 2) val = gelu_f(val);
        if (res) val += res[rb + col];
        if (C)   C[rb + col] = val;
        if (Cbf) Cbf[rb + col] = f2bf(val);
      }
    }
  }
}

// ---------------- flash attention, bf16 in, bf16 out ----------------
__global__ __launch_bounds__(256) void attn_kernel(
    const short* __restrict__ q, const short* __restrict__ kv, short* __restrict__ o)
{
  __shared__ short Kls[64][104];
  __shared__ short Vt[96][72];
  __shared__ short Pls[4][16][72];

  const int tid = threadIdx.x, lane = tid & 63, w = tid >> 6;
  const int l15 = lane & 15, l4 = lane >> 4;
  const int qt = blockIdx.x & 15;
  const int bh = blockIdx.x >> 4;
  const int h = bh & 7, b = bh >> 3;
  const int qb = qt * 64;
  const int qw = qb + w * 16;

  short8v qf[3];
  {
    const short* qp = q + ((size_t)(b * Ss + qw + l15)) * Dd + h * HDh + l4 * 8;
    #pragma unroll
    for (int kk = 0; kk < 3; ++kk) qf[kk] = *(const short8v*)(qp + kk * 32);
  }

  const f32x4 zz = {0.f, 0.f, 0.f, 0.f};
  f32x4 Oa[6];
  #pragma unroll
  for (int fn = 0; fn < 6; ++fn) Oa[fn] = zz;
  float mrow[4], lrow[4];
  #pragma unroll
  for (int r = 0; r < 4; ++r) { mrow[r] = -3.0e38f; lrow[r] = 0.f; }

  const size_t kvbase = (size_t)b * KVr;

  for (int t = 0; t < 33; ++t) {
    int k0 = t * 64;
    bool l2r_vis = (k0 <= Ss) && (k0 - 1 <= qb + 63);
    int rmaxk = (k0 + 63 > 2 * Ss) ? 2 * Ss : (k0 + 63);
    bool r2l_vis = (k0 + 63 >= Ss + 1) && (rmaxk - (Ss + 1) >= qb);
    if (!(t == 0 || l2r_vis || r2l_vis)) continue;

    __syncthreads();
    #pragma unroll
    for (int i = 0; i < 3; ++i) {
      int id = i * 256 + tid;          // 768 chunk jobs: 64 rows x 12 chunks
      int row = id / 12, cc = (id % 12) * 8;
      const short* kp = kv + (kvbase + k0 + row) * 1536 + h * HDh + cc;
      short8v k8 = *(const short8v*)kp;
      *(short8v*)&Kls[row][cc] = k8;
      short8v v8 = *(const short8v*)(kp + 768);
      #pragma unroll
      for (int j = 0; j < 8; ++j) Vt[cc + j][row] = v8[j];
    }
    __syncthreads();

    f32x4 sc[4];
    #pragma unroll
    for (int nt = 0; nt < 4; ++nt) {
      f32x4 d = zz;
      #pragma unroll
      for (int kk = 0; kk < 3; ++kk) {
        short8v kf = *(const short8v*)&Kls[nt * 16 + l15][kk * 32 + l4 * 8];
        d = __builtin_amdgcn_mfma_f32_16x16x32_bf16(qf[kk], kf, d, 0, 0, 0);
      }
      sc[nt] = d;
    }
    float tmax[4] = {-3.0e38f, -3.0e38f, -3.0e38f, -3.0e38f};
    #pragma unroll
    for (int nt = 0; nt < 4; ++nt)
      #pragma unroll
      for (int r = 0; r < 4; ++r) {
        int qg = qw + l4 * 4 + r;
        int j = k0 + nt * 16 + l15;
        bool vis = (j == 0) ||
                   (j >= 1 && j <= Ss && (j - 1) <= qg) ||
                   (j >= Ss + 1 && j <= 2 * Ss && (j - (Ss + 1)) >= qg);
        if (!vis) sc[nt][r] = -3.0e38f;
        tmax[r] = fmaxf(tmax[r], sc[nt][r]);
      }
    #pragma unroll
    for (int r = 0; r < 4; ++r) {
      #pragma unroll
      for (int off = 8; off >= 1; off >>= 1) tmax[r] = fmaxf(tmax[r], __shfl_xor(tmax[r], off));
    }
    float scl[4];
    #pragma unroll
    for (int r = 0; r < 4; ++r) {
      float mnew = fmaxf(mrow[r], tmax[r]);
      scl[r] = __expf(mrow[r] - mnew);
      mrow[r] = mnew;
    }
    #pragma unroll
    for (int fn = 0; fn < 6; ++fn)
      #pragma unroll
      for (int r = 0; r < 4; ++r) Oa[fn][r] *= scl[r];
    float lad[4] = {0.f, 0.f, 0.f, 0.f};
    #pragma unroll
    for (int nt = 0; nt < 4; ++nt)
      #pragma unroll
      for (int r = 0; r < 4; ++r) {
        float p = __expf(sc[nt][r] - mrow[r]);
        lad[r] += p;
        Pls[w][l4 * 4 + r][nt * 16 + l15] = f2bf(p);
      }
    #pragma unroll
    for (int r = 0; r < 4; ++r) {
      #pragma unroll
      for (int off = 8; off >= 1; off >>= 1) lad[r] += __shfl_xor(lad[r], off);
      lrow[r] = lrow[r] * scl[r] + lad[r];
    }
    __syncthreads();

    short8v pf[2];
    #pragma unroll
    for (int kk = 0; kk < 2; ++kk) pf[kk] = *(const short8v*)&Pls[w][l15][kk * 32 + l4 * 8];
    #pragma unroll
    for (int fn = 0; fn < 6; ++fn) {
      #pragma unroll
      for (int kk = 0; kk < 2; ++kk) {
        short8v vf = *(const short8v*)&Vt[fn * 16 + l15][kk * 32 + l4 * 8];
        Oa[fn] = __builtin_amdgcn_mfma_f32_16x16x32_bf16(pf[kk], vf, Oa[fn], 0, 0, 0);
      }
    }
  }

  #pragma unroll
  for (int fn = 0; fn < 6; ++fn)
    #pragma unroll
    for (int r = 0; r < 4; ++r) {
      int row = qw + l4 * 4 + r;
      int col = h * HDh + fn * 16 + l15;
      o[((size_t)(b * Ss + row)) * Dd + col] = f2bf(Oa[fn][r] / lrow[r]);
    }
}

// ---------------- thin (M=2) GEMM, split-K + reduce ----------------
__global__ __launch_bounds__(256) void thin1(const float* __restrict__ A, const float* __restrict__ W,
                                             float* __restrict__ part, int K, int N, int nblk)
{
  __shared__ float a0s[192], a1s[192];
  const int nb = blockIdx.x % nblk, ks = blockIdx.x / nblk;
  const int kl = K >> 4, kbeg = ks * kl;
  const int tid = threadIdx.x;
  for (int k = tid; k < kl; k += 256) { a0s[k] = A[kbeg + k]; a1s[k] = A[K + kbeg + k]; }
  __syncthreads();
  const int n = nb * 256 + tid;
  float acc0 = 0.f, acc1 = 0.f;
  for (int k = 0; k < kl; ++k) {
    float w = W[(size_t)(kbeg + k) * N + n];
    acc0 = fmaf(a0s[k], w, acc0);
    acc1 = fmaf(a1s[k], w, acc1);
  }
  part[(size_t)ks * 2 * N + n] = acc0;
  part[(size_t)ks * 2 * N + N + n] = acc1;
}

template<int ACT>
__global__ __launch_bounds__(256) void thin2(const float* __restrict__ part,
                                             const float* __restrict__ bias,
                                             float* __restrict__ C, int N)
{
  const int n = blockIdx.x * 256 + threadIdx.x;
  float a0 = bias[n], a1 = a0;
  for (int s = 0; s < 16; ++s) {
    a0 += part[(size_t)s * 2 * N + n];
    a1 += part[(size_t)s * 2 * N + N + n];
  }
  if (ACT == 2) { a0 = gelu_f(a0); a1 = gelu_f(a1); }
  C[n] = a0; C[N + n] = a1;
}

// ---------------- launch helpers ----------------
static void gemm_launch(int act, const short* A, const short* Bt, const float* bias,
                        const float* res, float* C, short* Cbf, int M, int N, int K,
                        float scale, hipStream_t s)
{
  int mt = (M + 127) >> 7, nt = N >> 7;
  dim3 grid(mt * nt), blk(256);
  if (act == 1)      gemm_bf<1><<<grid, blk, 0, s>>>(A, Bt, bias, res, C, Cbf, M, N, K, scale, mt);
  else if (act == 2) gemm_bf<2><<<grid, blk, 0, s>>>(A, Bt, bias, res, C, Cbf, M, N, K, scale, mt);
  else               gemm_bf<0><<<grid, blk, 0, s>>>(A, Bt, bias, res, C, Cbf, M, N, K, scale, mt);
}

static void conv_launch(const float* W, short* Wt, int K, int N, hipStream_t s)
{
  int nt = N >> 6, kt = K >> 6;
  convT<<<dim3(nt * kt), dim3(256), 0, s>>>(W, Wt, K, N, nt);
}

static void thin_launch(int act, const float* A, const float* W, const float* bias,
                        float* C, float* part, int K, int N, hipStream_t s)
{
  int nblk = N >> 8;
  thin1<<<dim3(nblk * 16), dim3(256), 0, s>>>(A, W, part, K, N, nblk);
  if (act == 2) thin2<2><<<dim3(nblk), dim3(256), 0, s>>>(part, bias, C, N);
  else          thin2<0><<<dim3(nblk), dim3(256), 0, s>>>(part, bias, C, N);
}

extern "C" void kernel_launch(void* const* d_in, const int* in_sizes, int n_in,
                              void* d_out, int out_size, void* d_ws, size_t ws_size,
                              hipStream_t stream)
{
  (void)in_sizes; (void)n_in; (void)out_size; (void)ws_size;
  const float* l2r      = (const float*)d_in[0];
  const float* r2l      = (const float*)d_in[1];
  const float* temb     = (const float*)d_in[2];
  const float* ln_l2r_s = (const float*)d_in[3];
  const float* ln_l2r_b = (const float*)d_in[4];
  const float* ln_r2l_s = (const float*)d_in[5];
  const float* ln_r2l_b = (const float*)d_in[6];
  const float* Wq = (const float*)d_in[7];
  const float* bq = (const float*)d_in[8];
  const float* Wk = (const float*)d_in[9];
  const float* bk = (const float*)d_in[10];
  const float* Wv = (const float*)d_in[11];
  const float* bv = (const float*)d_in[12];
  const float* Wo = (const float*)d_in[13];
  const float* bo = (const float*)d_in[14];
  const float* ff_ln_s = (const float*)d_in[15];
  const float* ff_ln_b = (const float*)d_in[16];
  const float* ff_w1 = (const float*)d_in[17];
  const float* ff_b1 = (const float*)d_in[18];
  const float* ff_w2 = (const float*)d_in[19];
  const float* ff_b2 = (const float*)d_in[20];
  const float* tm_w1 = (const float*)d_in[21];
  const float* tm_b1 = (const float*)d_in[22];
  const float* tm_w2 = (const float*)d_in[23];
  const float* tm_b2 = (const float*)d_in[24];
  const float* film_w = (const float*)d_in[25];
  const float* film_b = (const float*)d_in[26];
  const float* r_w1 = (const float*)d_in[27];
  const float* r_b1 = (const float*)d_in[28];
  const float* r_w2 = (const float*)d_in[29];
  const float* r_b2 = (const float*)d_in[30];
  const float* r_ln_s = (const float*)d_in[31];
  const float* r_ln_b = (const float*)d_in[32];
  const float* out_w = (const float*)d_in[33];
  const float* out_b = (const float*)d_in[34];

  uint8_t* base = (uint8_t*)d_ws;
  short* qin_bf  = (short*)(base + 0);          // 3,145,728
  short* alle_bf = (short*)(base + 3145728);    // 6,294,528
  short* qb      = (short*)(base + 9440256);    // 3,145,728
  short* kvbuf   = (short*)(base + 12585984);   // 12,589,056
  short* attn_bf = (short*)(base + 25175040);   // 3,145,728
  float* inputs  = (float*)(base + 28320768);   // 6,291,456
  float* xbuf    = (float*)(base + 34612224);   // 6,291,456
  short* xn_bf   = (short*)(base + 40903680);   // 3,145,728
  short* big_bf  = (short*)(base + 44049408);   // 12,582,912
  float* x2f     = (float*)(base + 56632320);   // 6,291,456
  short* x2bf    = (short*)(base + 62923776);   // 3,145,728
  float* uf      = (float*)(base + 66069504);   // 6,291,456 (u then u2)
  float* x3f     = (float*)(base + 72360960);   // 6,291,456
  short* x3bf    = (short*)(base + 78652416);   // 3,145,728
  short* x4bf    = (short*)(base + 81798144);   // 3,145,728
  short* wslot   = (short*)(base + 84943872);   // 4,718,592
  uint8_t* sm    = base + 89662464;
  float* part  = (float*)sm;                    // 393,216
  float* t1    = (float*)(sm + 393216);
  float* tb    = (float*)(sm + 417792);
  float* f0    = (float*)(sm + 442368);
  float* f1    = (float*)(sm + 454656);
  float* kvbia = (float*)(sm + 466944);
  short* outwT = (short*)(base + 0);            // alias over early region (49,152,000)

  const float qscale = 0.1020620726159658f;  // 1/sqrt(96)
  dim3 blk(256);

  // t-path (independent, f32)
  thin_launch(2, temb, tm_w1, tm_b1, t1, part, 768, 3072, stream);
  thin_launch(0, t1, tm_w2, tm_b2, tb, part, 3072, 3072, stream);
  thin_launch(0, tb, film_w,                       film_b,        f0, part, 3072, 1536, stream);
  thin_launch(0, tb, film_w + (size_t)3072 * 1536, film_b + 1536, f1, part, 3072, 1536, stream);

  prep_kernel<<<2048, blk, 0, stream>>>(l2r, r2l, ln_l2r_s, ln_l2r_b, ln_r2l_s, ln_r2l_b,
                                        inputs, qin_bf, alle_bf);
  temb_cvt<<<2, blk, 0, stream>>>(temb, alle_bf);

  // Q projection
  conv_launch(Wq, wslot, 768, 768, stream);
  gemm_launch(0, qin_bf, wslot, bq, nullptr, nullptr, qb, 2048, 768, 768, qscale, stream);
  // fused K|V projection
  conv_launch(Wk, wslot, 768, 768, stream);
  conv_launch(Wv, wslot + (size_t)768 * 768, 768, 768, stream);
  kvbias_kernel<<<6, blk, 0, stream>>>(bk, bv, kvbia);
  gemm_launch(0, alle_bf, wslot, kvbia, nullptr, nullptr, kvbuf, 4098, 1536, 768, 1.f, stream);

  attn_kernel<<<256, blk, 0, stream>>>(qb, kvbuf, attn_bf);

  conv_launch(Wo, wslot, 768, 768, stream);
  gemm_launch(0, attn_bf, wslot, bo, inputs, xbuf, nullptr, 2048, 768, 768, 1.f, stream);
  ln_kernel<<<2048, blk, 0, stream>>>(xbuf, ff_ln_s, ff_ln_b, nullptr, nullptr, xn_bf);

  conv_launch(ff_w1, wslot, 768, 3072, stream);
  gemm_launch(1, xn_bf, wslot, ff_b1, nullptr, nullptr, big_bf, 2048, 3072, 768, 1.f, stream);
  conv_launch(ff_w2, wslot, 3072, 768, stream);
  gemm_launch(0, big_bf, wslot, ff_b2, xbuf, x2f, x2bf, 2048, 768, 3072, 1.f, stream);

  // residual block 0
  conv_launch(r_w1, wslot, 768, 3072, stream);
  gemm_launch(2, x2bf, wslot, r_b1, nullptr, nullptr, big_bf, 2048, 3072, 768, 1.f, stream);
  conv_launch(r_w2, wslot, 3072, 768, stream);
  gemm_launch(0, big_bf, wslot, r_b2, x2f, uf, nullptr, 2048, 768, 3072, 1.f, stream);
  ln_kernel<<<2048, blk, 0, stream>>>(uf, r_ln_s, r_ln_b, f0, x3f, x3bf);

  // residual block 1
  conv_launch(r_w1 + (size_t)768 * 3072, wslot, 768, 3072, stream);
  gemm_launch(2, x3bf, wslot, r_b1 + 3072, nullptr, nullptr, big_bf, 2048, 3072, 768, 1.f, stream);
  conv_launch(r_w2 + (size_t)3072 * 768, wslot, 3072, 768, stream);
  gemm_launch(0, big_bf, wslot, r_b2 + 768, x3f, uf, nullptr, 2048, 768, 3072, 1.f, stream);
  ln_kernel<<<2048, blk, 0, stream>>>(uf, r_ln_s + 768, r_ln_b + 768, f1, nullptr, x4bf);

  // vocab projection (convert out_w late; aliases early-dead region)
  conv_launch(out_w, outwT, 768, 32000, stream);
  gemm_launch(0, x4bf, outwT, out_b, nullptr, (float*)d_out, nullptr, 2048, 32000, 768, 1.f, stream);
}

// Round 3
// 770.310 us; speedup vs baseline: 2.8308x; 1.1611x over previous
//
#include <hip/hip_runtime.h>
#include <cstdint>
#include <cstddef>

#define Bb 2
#define Ss 1024
#define Dd 768
#define Hh 8
#define HDh 96
#define Mm 3072
#define Vv 32000
#define KVr 2049   // 2S+1

typedef __attribute__((ext_vector_type(8))) short short8v;
typedef __attribute__((ext_vector_type(4))) short short4v;
typedef __attribute__((ext_vector_type(4))) float f32x4;

#define GL16(gp, lp) __builtin_amdgcn_global_load_lds( \
    (const __attribute__((address_space(1))) void*)(gp), \
    (__attribute__((address_space(3))) void*)(lp), 16, 0, 0)

static __device__ __forceinline__ short f2bf(float f) {
  union { float f; unsigned u; } x; x.f = f;
  unsigned r = (x.u + 0x7FFFu + ((x.u >> 16) & 1u)) >> 16;  // RNE
  return (short)(r & 0xFFFFu);
}

static __device__ __forceinline__ float gelu_f(float v) {
  float u = 0.7978845608028654f * (v + 0.044715f * v * v * v);
  float au = fabsf(u);
  float e = __expf(2.f * au);
  float t = 1.f - 2.f / (e + 1.f);     // tanh(|u|), safe at inf
  return 0.5f * v * (1.f + copysignf(t, u));
}

static __device__ __forceinline__ float blk_sum(float val, float* sh) {
  #pragma unroll
  for (int off = 32; off >= 1; off >>= 1) val += __shfl_xor(val, off);
  __syncthreads();
  if ((threadIdx.x & 63) == 0) sh[threadIdx.x >> 6] = val;
  __syncthreads();
  return sh[0] + sh[1] + sh[2] + sh[3];
}

// ---------------- prep: inputs(f32), qin(bf16), all_e rows (bf16) ----------------
__global__ __launch_bounds__(256) void prep_kernel(
    const float* __restrict__ l2r, const float* __restrict__ r2l,
    const float* __restrict__ s1, const float* __restrict__ b1,
    const float* __restrict__ s2, const float* __restrict__ b2,
    float* __restrict__ inputs, short* __restrict__ qin, short* __restrict__ all_e)
{
  __shared__ float sh[4];
  const int row = blockIdx.x, tid = threadIdx.x;
  const int b = row >> 10, s = row & 1023;
  const float* ap = l2r + (size_t)row * Dd;
  const float* cp = r2l + (size_t)row * Dd;
  float a0 = ap[tid], a1 = ap[tid + 256], a2 = ap[tid + 512];
  float c0 = cp[tid], c1 = cp[tid + 256], c2 = cp[tid + 512];
  float ma = blk_sum(a0 + a1 + a2, sh) * (1.f / 768.f);
  float mc = blk_sum(c0 + c1 + c2, sh) * (1.f / 768.f);
  float va = blk_sum((a0-ma)*(a0-ma) + (a1-ma)*(a1-ma) + (a2-ma)*(a2-ma), sh) * (1.f / 768.f);
  float vc = blk_sum((c0-mc)*(c0-mc) + (c1-mc)*(c1-mc) + (c2-mc)*(c2-mc), sh) * (1.f / 768.f);
  float ia = rsqrtf(va + 1e-6f), ic = rsqrtf(vc + 1e-6f);
  size_t ro = (size_t)row * Dd;
  size_t e1 = ((size_t)b * KVr + 1 + s) * Dd;
  size_t e2 = ((size_t)b * KVr + 1 + Ss + s) * Dd;
  float av[3] = {a0, a1, a2}, cv[3] = {c0, c1, c2};
  #pragma unroll
  for (int i = 0; i < 3; ++i) {
    int c = tid + i * 256;
    float an = (av[i] - ma) * ia * s1[c] + b1[c];
    float cn = (cv[i] - mc) * ic * s2[c] + b2[c];
    inputs[ro + c] = av[i] + cv[i];
    qin[ro + c]    = f2bf(an + cn);
    all_e[e1 + c]  = f2bf(an);
    all_e[e2 + c]  = f2bf(cn);
  }
}

__global__ __launch_bounds__(256) void temb_cvt(const float* __restrict__ temb,
                                                short* __restrict__ all_e)
{
  int b = blockIdx.x, tid = threadIdx.x;
  #pragma unroll
  for (int i = 0; i < 3; ++i)
    all_e[(size_t)b * KVr * Dd + tid + i * 256] = f2bf(temb[(size_t)b * Dd + tid + i * 256]);
}

// ---------------- LayerNorm (plain, bf16 out) ----------------
__global__ __launch_bounds__(256) void ln_kernel(
    const float* __restrict__ x, const float* __restrict__ sc, const float* __restrict__ bi,
    short* __restrict__ yb)
{
  __shared__ float sh[4];
  const int row = blockIdx.x, tid = threadIdx.x;
  const float* xr = x + (size_t)row * Dd;
  float v0 = xr[tid], v1 = xr[tid + 256], v2 = xr[tid + 512];
  float m = blk_sum(v0 + v1 + v2, sh) * (1.f / 768.f);
  float var = blk_sum((v0-m)*(v0-m) + (v1-m)*(v1-m) + (v2-m)*(v2-m), sh) * (1.f / 768.f);
  float inv = rsqrtf(var + 1e-6f);
  float vv[3] = {v0, v1, v2};
  #pragma unroll
  for (int i = 0; i < 3; ++i) {
    int c = tid + i * 256;
    yb[(size_t)row * Dd + c] = f2bf((vv[i] - m) * inv * sc[c] + bi[c]);
  }
}

// ---------------- split-K combine + LN + FiLM ----------------
// u = p0 + p1 + bias + res;  y = film_a * LN(u) + film_b
__global__ __launch_bounds__(256) void ln_comb(
    const float* __restrict__ p0, const float* __restrict__ p1,
    const float* __restrict__ bias, const float* __restrict__ res,
    const float* __restrict__ sc, const float* __restrict__ bi,
    const float* __restrict__ film, float* __restrict__ yf, short* __restrict__ yb)
{
  __shared__ float sh[4];
  const int row = blockIdx.x, tid = threadIdx.x;
  size_t ro = (size_t)row * Dd;
  float vv[3];
  #pragma unroll
  for (int i = 0; i < 3; ++i) {
    int c = tid + i * 256;
    vv[i] = p0[ro + c] + p1[ro + c] + bias[c] + res[ro + c];
  }
  float m = blk_sum(vv[0] + vv[1] + vv[2], sh) * (1.f / 768.f);
  float var = blk_sum((vv[0]-m)*(vv[0]-m) + (vv[1]-m)*(vv[1]-m) + (vv[2]-m)*(vv[2]-m), sh) * (1.f / 768.f);
  float inv = rsqrtf(var + 1e-6f);
  int bb = row >> 10;
  #pragma unroll
  for (int i = 0; i < 3; ++i) {
    int c = tid + i * 256;
    float o = (vv[i] - m) * inv * sc[c] + bi[c];
    o = film[(size_t)bb * 1536 + c] * o + film[(size_t)bb * 1536 + 768 + c];
    if (yf) yf[ro + c] = o;
    if (yb) yb[ro + c] = f2bf(o);
  }
}

// split-K combine for ff2: y = p0 + p1 + bias + res (f32 + bf16 out)
__global__ __launch_bounds__(256) void combine_kernel(
    const float* __restrict__ p0, const float* __restrict__ p1,
    const float* __restrict__ bias, const float* __restrict__ res,
    float* __restrict__ yf, short* __restrict__ yb)
{
  const int row = blockIdx.x, tid = threadIdx.x;
  size_t ro = (size_t)row * Dd;
  #pragma unroll
  for (int i = 0; i < 3; ++i) {
    int c = tid + i * 256;
    float v = p0[ro + c] + p1[ro + c] + bias[c] + res[ro + c];
    yf[ro + c] = v;
    yb[ro + c] = f2bf(v);
  }
}

// ---------------- weight convert+transpose: f32 [K][N] -> bf16 [N][K] ----------------
__global__ __launch_bounds__(256) void convT(const float* __restrict__ W, short* __restrict__ Wt,
                                             int K, int N, int ntile)
{
  __shared__ short T[64][72];
  const int bn = blockIdx.x % ntile, bk = blockIdx.x / ntile;
  const int k0 = bk * 64, n0 = bn * 64, tid = threadIdx.x;
  #pragma unroll
  for (int i = 0; i < 4; ++i) {
    int id = i * 256 + tid;
    int r = id >> 4, c4 = (id & 15) * 4;
    float4 w4 = *(const float4*)(W + (size_t)(k0 + r) * N + n0 + c4);
    T[c4 + 0][r] = f2bf(w4.x);
    T[c4 + 1][r] = f2bf(w4.y);
    T[c4 + 2][r] = f2bf(w4.z);
    T[c4 + 3][r] = f2bf(w4.w);
  }
  __syncthreads();
  #pragma unroll
  for (int i = 0; i < 4; ++i) {
    int id = i * 256 + tid;
    int n = id >> 4, k4 = (id & 15) * 4;
    short4v s = *(const short4v*)&T[n][k4];
    *(short4v*)(Wt + (size_t)(n0 + n) * K + k0 + k4) = s;
  }
}

// fused 4x (768x768) weight convert
__global__ __launch_bounds__(256) void convT4(const float* __restrict__ W0, const float* __restrict__ W1,
                                              const float* __restrict__ W2, const float* __restrict__ W3,
                                              short* __restrict__ Wt)
{
  __shared__ short T[64][72];
  const int wsel = blockIdx.x / 144, rem = blockIdx.x % 144;
  const float* W = wsel == 0 ? W0 : wsel == 1 ? W1 : wsel == 2 ? W2 : W3;
  short* dst = Wt + (size_t)wsel * 768 * 768;
  const int bn = rem % 12, bk = rem / 12;
  const int k0 = bk * 64, n0 = bn * 64, tid = threadIdx.x;
  #pragma unroll
  for (int i = 0; i < 4; ++i) {
    int id = i * 256 + tid;
    int r = id >> 4, c4 = (id & 15) * 4;
    float4 w4 = *(const float4*)(W + (size_t)(k0 + r) * 768 + n0 + c4);
    T[c4 + 0][r] = f2bf(w4.x);
    T[c4 + 1][r] = f2bf(w4.y);
    T[c4 + 2][r] = f2bf(w4.z);
    T[c4 + 3][r] = f2bf(w4.w);
  }
  __syncthreads();
  #pragma unroll
  for (int i = 0; i < 4; ++i) {
    int id = i * 256 + tid;
    int n = id >> 4, k4 = (id & 15) * 4;
    short4v s = *(const short4v*)&T[n][k4];
    *(short4v*)(dst + (size_t)(n0 + n) * 768 + k0 + k4) = s;
  }
}

__global__ __launch_bounds__(256) void kvbias_kernel(const float* __restrict__ bk,
                                                     const float* __restrict__ bv,
                                                     float* __restrict__ kvb)
{
  int i = blockIdx.x * 256 + threadIdx.x;
  if (i < 1536) kvb[i] = (i < 768) ? bk[i] : bv[i - 768];
}

// ---------------- bf16 MFMA GEMM: A[M][K] bf16, Bt[N][K] bf16 ----------------
// XCD-chunk-swizzled block mapping; optional split-K partial output.
template<int ACT>
__global__ __launch_bounds__(256) void gemm_bf(
    const short* __restrict__ A, const short* __restrict__ Bt,
    const float* __restrict__ bias, const float* __restrict__ res,
    float* __restrict__ C, short* __restrict__ Cbf, float* __restrict__ Cpart,
    int M, int N, int K, float scale, int mtiles, int ntiles, int ksplit)
{
  __shared__ short As[8192];   // [128][64] linear, content chunk-swizzled
  __shared__ short Bs[8192];
  const int tid = threadIdx.x, lane = tid & 63, wv = tid >> 6;
  const int l15 = lane & 15, l4 = lane >> 4;

  // bijective XCD chunk swizzle (m204)
  const int nwg = gridDim.x;
  const int qc = nwg >> 3, rc = nwg & 7;
  const int xcd = blockIdx.x & 7, idx = blockIdx.x >> 3;
  const int wgid = (xcd < rc ? xcd * (qc + 1) : rc * (qc + 1) + (xcd - rc) * qc) + idx;
  const int by = wgid % mtiles;
  const int rest = wgid / mtiles;
  const int bx = rest % ntiles;
  const int sp = rest / ntiles;
  const int kper = K / ksplit;
  const int kbeg = sp * kper, kend = kbeg + kper;

  const int m0 = by * 128, n0 = bx * 128;
  const int wm = (wv >> 1) * 64, wn = (wv & 1) * 64;
  const int r8 = lane >> 3, c8 = lane & 7;
  const int csw = ((c8 ^ r8) << 3);   // pre-swizzled source chunk offset (shorts)

  f32x4 acc[4][4];
  const f32x4 zz = {0.f, 0.f, 0.f, 0.f};
  #pragma unroll
  for (int i = 0; i < 4; ++i)
    #pragma unroll
    for (int j = 0; j < 4; ++j) acc[i][j] = zz;

  const short* Ab = A + (size_t)m0 * K + csw;
  const short* Bp = Bt + (size_t)n0 * K + csw;

  for (int k0 = kbeg; k0 < kend; k0 += 64) {
    __syncthreads();
    #pragma unroll
    for (int i = 0; i < 4; ++i) {
      int row = wv * 32 + i * 8 + r8;
      GL16(Ab + (size_t)row * K + k0, &As[(wv * 4 + i) * 512]);
      GL16(Bp + (size_t)row * K + k0, &Bs[(wv * 4 + i) * 512]);
    }
    __syncthreads();
    short8v af[2][4], bfv[2][4];
    #pragma unroll
    for (int kk = 0; kk < 2; ++kk) {
      #pragma unroll
      for (int mi = 0; mi < 4; ++mi)
        af[kk][mi] = *(const short8v*)&As[(wm + mi * 16 + l15) * 64 + ((((kk << 2) | l4) ^ (l15 & 7)) << 3)];
      #pragma unroll
      for (int ni = 0; ni < 4; ++ni)
        bfv[kk][ni] = *(const short8v*)&Bs[(wn + ni * 16 + l15) * 64 + ((((kk << 2) | l4) ^ (l15 & 7)) << 3)];
    }
    #pragma unroll
    for (int kk = 0; kk < 2; ++kk)
      #pragma unroll
      for (int mi = 0; mi < 4; ++mi)
        #pragma unroll
        for (int ni = 0; ni < 4; ++ni)
          acc[mi][ni] = __builtin_amdgcn_mfma_f32_16x16x32_bf16(af[kk][mi], bfv[kk][ni], acc[mi][ni], 0, 0, 0);
  }

  if (Cpart) {
    float* Cp = Cpart + (size_t)sp * M * N;
    #pragma unroll
    for (int mi = 0; mi < 4; ++mi)
      #pragma unroll
      for (int r = 0; r < 4; ++r) {
        int row = m0 + wm + mi * 16 + l4 * 4 + r;
        if (row >= M) continue;
        size_t rb = (size_t)row * N;
        #pragma unroll
        for (int ni = 0; ni < 4; ++ni)
          Cp[rb + n0 + wn + ni * 16 + l15] = acc[mi][ni][r];
      }
    return;
  }

  #pragma unroll
  for (int mi = 0; mi < 4; ++mi) {
    #pragma unroll
    for (int r = 0; r < 4; ++r) {
      int row = m0 + wm + mi * 16 + l4 * 4 + r;
      if (row >= M) continue;
      size_t rb = (size_t)row * N;
      #pragma unroll
      for (int ni = 0; ni < 4; ++ni) {
        int col = n0 + wn + ni * 16 + l15;
        float val = (acc[mi][ni][r] + bias[col]) * scale;
        if (ACT == 1) val = fmaxf(val, 0.f);
        if (ACT == 2) val = gelu_f(val);
        if (res) val += res[rb + col];
        if (C)   C[rb + col] = val;
        if (Cbf) Cbf[rb + col] = f2bf(val);
      }
    }
  }
}

// ---------------- flash attention, bf16 in, bf16 out ----------------
__global__ __launch_bounds__(256) void attn_kernel(
    const short* __restrict__ q, const short* __restrict__ kv, short* __restrict__ o)
{
  __shared__ short Kls[64][104];
  __shared__ short Vt[96][72];
  __shared__ short Pls[4][16][72];

  const int tid = threadIdx.x, lane = tid & 63, w = tid >> 6;
  const int l15 = lane & 15, l4 = lane >> 4;
  const int qt = blockIdx.x & 15;
  const int bh = blockIdx.x >> 4;
  const int h = bh & 7, b = bh >> 3;
  const int qb = qt * 64;
  const int qw = qb + w * 16;

  short8v qf[3];
  {
    const short* qp = q + ((size_t)(b * Ss + qw + l15)) * Dd + h * HDh + l4 * 8;
    #pragma unroll
    for (int kk = 0; kk < 3; ++kk) qf[kk] = *(const short8v*)(qp + kk * 32);
  }

  const f32x4 zz = {0.f, 0.f, 0.f, 0.f};
  f32x4 Oa[6];
  #pragma unroll
  for (int fn = 0; fn < 6; ++fn) Oa[fn] = zz;
  float mrow[4], lrow[4];
  #pragma unroll
  for (int r = 0; r < 4; ++r) { mrow[r] = -3.0e38f; lrow[r] = 0.f; }

  const size_t kvbase = (size_t)b * KVr;

  for (int t = 0; t < 33; ++t) {
    int k0 = t * 64;
    bool l2r_vis = (k0 <= Ss) && (k0 - 1 <= qb + 63);
    int rmaxk = (k0 + 63 > 2 * Ss) ? 2 * Ss : (k0 + 63);
    bool r2l_vis = (k0 + 63 >= Ss + 1) && (rmaxk - (Ss + 1) >= qb);
    if (!(t == 0 || l2r_vis || r2l_vis)) continue;

    __syncthreads();
    #pragma unroll
    for (int i = 0; i < 3; ++i) {
      int id = i * 256 + tid;          // 768 chunk jobs: 64 rows x 12 chunks
      int row = id / 12, cc = (id % 12) * 8;
      const short* kp = kv + (kvbase + k0 + row) * 1536 + h * HDh + cc;
      short8v k8 = *(const short8v*)kp;
      *(short8v*)&Kls[row][cc] = k8;
      short8v v8 = *(const short8v*)(kp + 768);
      #pragma unroll
      for (int j = 0; j < 8; ++j) Vt[cc + j][row] = v8[j];
    }
    __syncthreads();

    f32x4 sc[4];
    #pragma unroll
    for (int nt = 0; nt < 4; ++nt) {
      f32x4 d = zz;
      #pragma unroll
      for (int kk = 0; kk < 3; ++kk) {
        short8v kf = *(const short8v*)&Kls[nt * 16 + l15][kk * 32 + l4 * 8];
        d = __builtin_amdgcn_mfma_f32_16x16x32_bf16(qf[kk], kf, d, 0, 0, 0);
      }
      sc[nt] = d;
    }
    float tmax[4] = {-3.0e38f, -3.0e38f, -3.0e38f, -3.0e38f};
    #pragma unroll
    for (int nt = 0; nt < 4; ++nt)
      #pragma unroll
      for (int r = 0; r < 4; ++r) {
        int qg = qw + l4 * 4 + r;
        int j = k0 + nt * 16 + l15;
        bool vis = (j == 0) ||
                   (j >= 1 && j <= Ss && (j - 1) <= qg) ||
                   (j >= Ss + 1 && j <= 2 * Ss && (j - (Ss + 1)) >= qg);
        if (!vis) sc[nt][r] = -3.0e38f;
        tmax[r] = fmaxf(tmax[r], sc[nt][r]);
      }
    #pragma unroll
    for (int r = 0; r < 4; ++r) {
      #pragma unroll
      for (int off = 8; off >= 1; off >>= 1) tmax[r] = fmaxf(tmax[r], __shfl_xor(tmax[r], off));
    }
    float scl[4];
    #pragma unroll
    for (int r = 0; r < 4; ++r) {
      float mnew = fmaxf(mrow[r], tmax[r]);
      scl[r] = __expf(mrow[r] - mnew);
      mrow[r] = mnew;
    }
    #pragma unroll
    for (int fn = 0; fn < 6; ++fn)
      #pragma unroll
      for (int r = 0; r < 4; ++r) Oa[fn][r] *= scl[r];
    float lad[4] = {0.f, 0.f, 0.f, 0.f};
    #pragma unroll
    for (int nt = 0; nt < 4; ++nt)
      #pragma unroll
      for (int r = 0; r < 4; ++r) {
        float p = __expf(sc[nt][r] - mrow[r]);
        lad[r] += p;
        Pls[w][l4 * 4 + r][nt * 16 + l15] = f2bf(p);
      }
    #pragma unroll
    for (int r = 0; r < 4; ++r) {
      #pragma unroll
      for (int off = 8; off >= 1; off >>= 1) lad[r] += __shfl_xor(lad[r], off);
      lrow[r] = lrow[r] * scl[r] + lad[r];
    }
    __syncthreads();

    short8v pf[2];
    #pragma unroll
    for (int kk = 0; kk < 2; ++kk) pf[kk] = *(const short8v*)&Pls[w][l15][kk * 32 + l4 * 8];
    #pragma unroll
    for (int fn = 0; fn < 6; ++fn) {
      #pragma unroll
      for (int kk = 0; kk < 2; ++kk) {
        short8v vf = *(const short8v*)&Vt[fn * 16 + l15][kk * 32 + l4 * 8];
        Oa[fn] = __builtin_amdgcn_mfma_f32_16x16x32_bf16(pf[kk], vf, Oa[fn], 0, 0, 0);
      }
    }
  }

  #pragma unroll
  for (int fn = 0; fn < 6; ++fn)
    #pragma unroll
    for (int r = 0; r < 4; ++r) {
      int row = qw + l4 * 4 + r;
      int col = h * HDh + fn * 16 + l15;
      o[((size_t)(b * Ss + row)) * Dd + col] = f2bf(Oa[fn][r] / lrow[r]);
    }
}

// ---------------- thin (M=2) GEMM, split-K + reduce ----------------
__global__ __launch_bounds__(256) void thin1(const float* __restrict__ A, const float* __restrict__ W,
                                             float* __restrict__ part, int K, int N, int nblk)
{
  __shared__ float a0s[192], a1s[192];
  const int nb = blockIdx.x % nblk, ks = blockIdx.x / nblk;
  const int kl = K >> 4, kbeg = ks * kl;
  const int tid = threadIdx.x;
  for (int k = tid; k < kl; k += 256) { a0s[k] = A[kbeg + k]; a1s[k] = A[K + kbeg + k]; }
  __syncthreads();
  const int n = nb * 256 + tid;
  float acc0 = 0.f, acc1 = 0.f;
  for (int k = 0; k < kl; ++k) {
    float w = W[(size_t)(kbeg + k) * N + n];
    acc0 = fmaf(a0s[k], w, acc0);
    acc1 = fmaf(a1s[k], w, acc1);
  }
  part[(size_t)ks * 2 * N + n] = acc0;
  part[(size_t)ks * 2 * N + N + n] = acc1;
}

template<int ACT>
__global__ __launch_bounds__(256) void thin2(const float* __restrict__ part,
                                             const float* __restrict__ bias,
                                             float* __restrict__ C, int N)
{
  const int n = blockIdx.x * 256 + threadIdx.x;
  float a0 = bias[n], a1 = a0;
  for (int s = 0; s < 16; ++s) {
    a0 += part[(size_t)s * 2 * N + n];
    a1 += part[(size_t)s * 2 * N + N + n];
  }
  if (ACT == 2) { a0 = gelu_f(a0); a1 = gelu_f(a1); }
  C[n] = a0; C[N + n] = a1;
}

// ---------------- launch helpers ----------------
static void gemm_launch(int act, const short* A, const short* Bt, const float* bias,
                        const float* res, float* C, short* Cbf, float* Cpart,
                        int M, int N, int K, float scale, int ksplit, hipStream_t s)
{
  int mt = (M + 127) >> 7, nt = N >> 7;
  dim3 grid(mt * nt * ksplit), blk(256);
  if (act == 1)      gemm_bf<1><<<grid, blk, 0, s>>>(A, Bt, bias, res, C, Cbf, Cpart, M, N, K, scale, mt, nt, ksplit);
  else if (act == 2) gemm_bf<2><<<grid, blk, 0, s>>>(A, Bt, bias, res, C, Cbf, Cpart, M, N, K, scale, mt, nt, ksplit);
  else               gemm_bf<0><<<grid, blk, 0, s>>>(A, Bt, bias, res, C, Cbf, Cpart, M, N, K, scale, mt, nt, ksplit);
}

static void conv_launch(const float* W, short* Wt, int K, int N, hipStream_t s)
{
  int nt = N >> 6, kt = K >> 6;
  convT<<<dim3(nt * kt), dim3(256), 0, s>>>(W, Wt, K, N, nt);
}

static void thin_launch(int act, const float* A, const float* W, const float* bias,
                        float* C, float* part, int K, int N, hipStream_t s)
{
  int nblk = N >> 8;
  thin1<<<dim3(nblk * 16), dim3(256), 0, s>>>(A, W, part, K, N, nblk);
  if (act == 2) thin2<2><<<dim3(nblk), dim3(256), 0, s>>>(part, bias, C, N);
  else          thin2<0><<<dim3(nblk), dim3(256), 0, s>>>(part, bias, C, N);
}

extern "C" void kernel_launch(void* const* d_in, const int* in_sizes, int n_in,
                              void* d_out, int out_size, void* d_ws, size_t ws_size,
                              hipStream_t stream)
{
  (void)in_sizes; (void)n_in; (void)out_size; (void)ws_size;
  const float* l2r      = (const float*)d_in[0];
  const float* r2l      = (const float*)d_in[1];
  const float* temb     = (const float*)d_in[2];
  const float* ln_l2r_s = (const float*)d_in[3];
  const float* ln_l2r_b = (const float*)d_in[4];
  const float* ln_r2l_s = (const float*)d_in[5];
  const float* ln_r2l_b = (const float*)d_in[6];
  const float* Wq = (const float*)d_in[7];
  const float* bq = (const float*)d_in[8];
  const float* Wk = (const float*)d_in[9];
  const float* bk = (const float*)d_in[10];
  const float* Wv = (const float*)d_in[11];
  const float* bv = (const float*)d_in[12];
  const float* Wo = (const float*)d_in[13];
  const float* bo = (const float*)d_in[14];
  const float* ff_ln_s = (const float*)d_in[15];
  const float* ff_ln_b = (const float*)d_in[16];
  const float* ff_w1 = (const float*)d_in[17];
  const float* ff_b1 = (const float*)d_in[18];
  const float* ff_w2 = (const float*)d_in[19];
  const float* ff_b2 = (const float*)d_in[20];
  const float* tm_w1 = (const float*)d_in[21];
  const float* tm_b1 = (const float*)d_in[22];
  const float* tm_w2 = (const float*)d_in[23];
  const float* tm_b2 = (const float*)d_in[24];
  const float* film_w = (const float*)d_in[25];
  const float* film_b = (const float*)d_in[26];
  const float* r_w1 = (const float*)d_in[27];
  const float* r_b1 = (const float*)d_in[28];
  const float* r_w2 = (const float*)d_in[29];
  const float* r_b2 = (const float*)d_in[30];
  const float* r_ln_s = (const float*)d_in[31];
  const float* r_ln_b = (const float*)d_in[32];
  const float* out_w = (const float*)d_in[33];
  const float* out_b = (const float*)d_in[34];

  uint8_t* base = (uint8_t*)d_ws;
  short* qin_bf  = (short*)(base + 0);          // 3,145,728
  short* alle_bf = (short*)(base + 3145728);    // 6,294,528
  short* qb      = (short*)(base + 9440256);    // 3,145,728
  short* kvbuf   = (short*)(base + 12585984);   // 12,589,056
  short* attn_bf = (short*)(base + 25175040);   // 3,145,728
  float* inputs  = (float*)(base + 28320768);   // 6,291,456
  float* xbuf    = (float*)(base + 34612224);   // 6,291,456
  short* xn_bf   = (short*)(base + 40903680);   // 3,145,728
  short* big_bf  = (short*)(base + 44049408);   // 12,582,912
  float* x2f     = (float*)(base + 56632320);   // 6,291,456
  short* x2bf    = (short*)(base + 62923776);   // 3,145,728
  float* x3f     = (float*)(base + 72360960);   // 6,291,456
  short* x3bf    = (short*)(base + 78652416);   // 3,145,728
  short* x4bf    = (short*)(base + 81798144);   // 3,145,728
  short* wslot   = (short*)(base + 84943872);   // 4,718,592
  uint8_t* sm    = base + 89662464;
  float* part2 = (float*)sm;                    // 393,216 (thin split-K)
  float* t1    = (float*)(sm + 393216);
  float* tb    = (float*)(sm + 417792);
  float* f0    = (float*)(sm + 442368);
  float* f1    = (float*)(sm + 454656);
  float* kvbia = (float*)(sm + 466944);
  // split-K partials for the (2048x768xK=3072) GEMMs: alias dead early region
  float* partK = (float*)(base + 0);            // 2 x 6,291,456 = 12,582,912 (< kvbuf end? starts at 0, ends 12.58M, kvbuf at 12.59M — used only after attention)
  short* outwT = (short*)(base + 0);            // 49,152,000 (used only after all split-K)

  const float qscale = 0.1020620726159658f;  // 1/sqrt(96)
  dim3 blk(256);

  // t-path (independent, f32)
  thin_launch(2, temb, tm_w1, tm_b1, t1, part2, 768, 3072, stream);
  thin_launch(0, t1, tm_w2, tm_b2, tb, part2, 3072, 3072, stream);
  thin_launch(0, tb, film_w,                       film_b,        f0, part2, 3072, 1536, stream);
  thin_launch(0, tb, film_w + (size_t)3072 * 1536, film_b + 1536, f1, part2, 3072, 1536, stream);

  prep_kernel<<<2048, blk, 0, stream>>>(l2r, r2l, ln_l2r_s, ln_l2r_b, ln_r2l_s, ln_r2l_b,
                                        inputs, qin_bf, alle_bf);
  temb_cvt<<<2, blk, 0, stream>>>(temb, alle_bf);

  // fused QKVO weight conversion
  convT4<<<dim3(576), blk, 0, stream>>>(Wq, Wk, Wv, Wo, wslot);
  kvbias_kernel<<<6, blk, 0, stream>>>(bk, bv, kvbia);

  gemm_launch(0, qin_bf, wslot, bq, nullptr, nullptr, qb, nullptr, 2048, 768, 768, qscale, 1, stream);
  gemm_launch(0, alle_bf, wslot + (size_t)768 * 768, kvbia, nullptr, nullptr, kvbuf, nullptr, 4098, 1536, 768, 1.f, 1, stream);

  attn_kernel<<<256, blk, 0, stream>>>(qb, kvbuf, attn_bf);

  gemm_launch(0, attn_bf, wslot + (size_t)3 * 768 * 768, bo, inputs, xbuf, nullptr, nullptr, 2048, 768, 768, 1.f, 1, stream);
  ln_kernel<<<2048, blk, 0, stream>>>(xbuf, ff_ln_s, ff_ln_b, xn_bf);

  conv_launch(ff_w1, wslot, 768, 3072, stream);
  gemm_launch(1, xn_bf, wslot, ff_b1, nullptr, nullptr, big_bf, nullptr, 2048, 3072, 768, 1.f, 1, stream);
  conv_launch(ff_w2, wslot, 3072, 768, stream);
  gemm_launch(0, big_bf, wslot, nullptr, nullptr, nullptr, nullptr, partK, 2048, 768, 3072, 1.f, 2, stream);
  combine_kernel<<<2048, blk, 0, stream>>>(partK, partK + (size_t)2048 * 768, ff_b2, xbuf, x2f, x2bf);

  // residual block 0
  conv_launch(r_w1, wslot, 768, 3072, stream);
  gemm_launch(2, x2bf, wslot, r_b1, nullptr, nullptr, big_bf, nullptr, 2048, 3072, 768, 1.f, 1, stream);
  conv_launch(r_w2, wslot, 3072, 768, stream);
  gemm_launch(0, big_bf, wslot, nullptr, nullptr, nullptr, nullptr, partK, 2048, 768, 3072, 1.f, 2, stream);
  ln_comb<<<2048, blk, 0, stream>>>(partK, partK + (size_t)2048 * 768, r_b2, x2f,
                                    r_ln_s, r_ln_b, f0, x3f, x3bf);

  // residual block 1
  conv_launch(r_w1 + (size_t)768 * 3072, wslot, 768, 3072, stream);
  gemm_launch(2, x3bf, wslot, r_b1 + 3072, nullptr, nullptr, big_bf, nullptr, 2048, 3072, 768, 1.f, 1, stream);
  conv_launch(r_w2 + (size_t)3072 * 768, wslot, 3072, 768, stream);
  gemm_launch(0, big_bf, wslot, nullptr, nullptr, nullptr, nullptr, partK, 2048, 768, 3072, 1.f, 2, stream);
  ln_comb<<<2048, blk, 0, stream>>>(partK, partK + (size_t)2048 * 768, r_b2 + 768, x3f,
                                    r_ln_s + 768, r_ln_b + 768, f1, nullptr, x4bf);

  // vocab projection (convert out_w late; aliases early-dead region)
  conv_launch(out_w, outwT, 768, 32000, stream);
  gemm_launch(0, x4bf, outwT, out_b, nullptr, (float*)d_out, nullptr, nullptr, 2048, 32000, 768, 1.f, 1, stream);
}

// Round 5
// 693.210 us; speedup vs baseline: 3.1457x; 1.1112x over previous
//
#include <hip/hip_runtime.h>
#include <cstdint>
#include <cstddef>

#define Bb 2
#define Ss 1024
#define Dd 768
#define Hh 8
#define HDh 96
#define Mm 3072
#define Vv 32000
#define KVr 2049   // 2S+1

typedef __attribute__((ext_vector_type(8))) short short8v;
typedef __attribute__((ext_vector_type(4))) short short4v;
typedef __attribute__((ext_vector_type(4))) float f32x4;

#define GL16(gp, lp) __builtin_amdgcn_global_load_lds( \
    (const __attribute__((address_space(1))) void*)(gp), \
    (__attribute__((address_space(3))) void*)(lp), 16, 0, 0)

static __device__ __forceinline__ short f2bf(float f) {
  union { float f; unsigned u; } x; x.f = f;
  unsigned r = (x.u + 0x7FFFu + ((x.u >> 16) & 1u)) >> 16;  // RNE
  return (short)(r & 0xFFFFu);
}

static __device__ __forceinline__ float gelu_f(float v) {
  float u = 0.7978845608028654f * (v + 0.044715f * v * v * v);
  float au = fabsf(u);
  float e = __expf(2.f * au);
  float t = 1.f - 2.f / (e + 1.f);     // tanh(|u|), safe at inf
  return 0.5f * v * (1.f + copysignf(t, u));
}

static __device__ __forceinline__ float blk_sum(float val, float* sh) {
  #pragma unroll
  for (int off = 32; off >= 1; off >>= 1) val += __shfl_xor(val, off);
  __syncthreads();
  if ((threadIdx.x & 63) == 0) sh[threadIdx.x >> 6] = val;
  __syncthreads();
  return sh[0] + sh[1] + sh[2] + sh[3];
}

// ---------------- prep: inputs(f32), qin(bf16), all_e rows (bf16), temb rows ----------------
__global__ __launch_bounds__(256) void prep_kernel(
    const float* __restrict__ l2r, const float* __restrict__ r2l,
    const float* __restrict__ temb,
    const float* __restrict__ s1, const float* __restrict__ b1,
    const float* __restrict__ s2, const float* __restrict__ b2,
    float* __restrict__ inputs, short* __restrict__ qin, short* __restrict__ all_e)
{
  __shared__ float sh[4];
  const int tid = threadIdx.x;
  if (blockIdx.x >= 2048) {   // temb rows of all_e
    int b = blockIdx.x - 2048;
    #pragma unroll
    for (int i = 0; i < 3; ++i)
      all_e[(size_t)b * KVr * Dd + tid + i * 256] = f2bf(temb[(size_t)b * Dd + tid + i * 256]);
    return;
  }
  const int row = blockIdx.x;
  const int b = row >> 10, s = row & 1023;
  const float* ap = l2r + (size_t)row * Dd;
  const float* cp = r2l + (size_t)row * Dd;
  float a0 = ap[tid], a1 = ap[tid + 256], a2 = ap[tid + 512];
  float c0 = cp[tid], c1 = cp[tid + 256], c2 = cp[tid + 512];
  float ma = blk_sum(a0 + a1 + a2, sh) * (1.f / 768.f);
  float mc = blk_sum(c0 + c1 + c2, sh) * (1.f / 768.f);
  float va = blk_sum((a0-ma)*(a0-ma) + (a1-ma)*(a1-ma) + (a2-ma)*(a2-ma), sh) * (1.f / 768.f);
  float vc = blk_sum((c0-mc)*(c0-mc) + (c1-mc)*(c1-mc) + (c2-mc)*(c2-mc), sh) * (1.f / 768.f);
  float ia = rsqrtf(va + 1e-6f), ic = rsqrtf(vc + 1e-6f);
  size_t ro = (size_t)row * Dd;
  size_t e1 = ((size_t)b * KVr + 1 + s) * Dd;
  size_t e2 = ((size_t)b * KVr + 1 + Ss + s) * Dd;
  float av[3] = {a0, a1, a2}, cv[3] = {c0, c1, c2};
  #pragma unroll
  for (int i = 0; i < 3; ++i) {
    int c = tid + i * 256;
    float an = (av[i] - ma) * ia * s1[c] + b1[c];
    float cn = (cv[i] - mc) * ic * s2[c] + b2[c];
    inputs[ro + c] = av[i] + cv[i];
    qin[ro + c]    = f2bf(an + cn);
    all_e[e1 + c]  = f2bf(an);
    all_e[e2 + c]  = f2bf(cn);
  }
}

// ---------------- LayerNorm (plain, bf16 out) ----------------
__global__ __launch_bounds__(256) void ln_kernel(
    const float* __restrict__ x, const float* __restrict__ sc, const float* __restrict__ bi,
    short* __restrict__ yb)
{
  __shared__ float sh[4];
  const int row = blockIdx.x, tid = threadIdx.x;
  const float* xr = x + (size_t)row * Dd;
  float v0 = xr[tid], v1 = xr[tid + 256], v2 = xr[tid + 512];
  float m = blk_sum(v0 + v1 + v2, sh) * (1.f / 768.f);
  float var = blk_sum((v0-m)*(v0-m) + (v1-m)*(v1-m) + (v2-m)*(v2-m), sh) * (1.f / 768.f);
  float inv = rsqrtf(var + 1e-6f);
  float vv[3] = {v0, v1, v2};
  #pragma unroll
  for (int i = 0; i < 3; ++i) {
    int c = tid + i * 256;
    yb[(size_t)row * Dd + c] = f2bf((vv[i] - m) * inv * sc[c] + bi[c]);
  }
}

// ---------------- split-K combine + LN + FiLM ----------------
__global__ __launch_bounds__(256) void ln_comb(
    const float* __restrict__ p0, const float* __restrict__ p1,
    const float* __restrict__ bias, const float* __restrict__ res,
    const float* __restrict__ sc, const float* __restrict__ bi,
    const float* __restrict__ film, float* __restrict__ yf, short* __restrict__ yb)
{
  __shared__ float sh[4];
  const int row = blockIdx.x, tid = threadIdx.x;
  size_t ro = (size_t)row * Dd;
  float vv[3];
  #pragma unroll
  for (int i = 0; i < 3; ++i) {
    int c = tid + i * 256;
    vv[i] = p0[ro + c] + p1[ro + c] + bias[c] + res[ro + c];
  }
  float m = blk_sum(vv[0] + vv[1] + vv[2], sh) * (1.f / 768.f);
  float var = blk_sum((vv[0]-m)*(vv[0]-m) + (vv[1]-m)*(vv[1]-m) + (vv[2]-m)*(vv[2]-m), sh) * (1.f / 768.f);
  float inv = rsqrtf(var + 1e-6f);
  int bb = row >> 10;
  #pragma unroll
  for (int i = 0; i < 3; ++i) {
    int c = tid + i * 256;
    float o = (vv[i] - m) * inv * sc[c] + bi[c];
    o = film[(size_t)bb * 1536 + c] * o + film[(size_t)bb * 1536 + 768 + c];
    if (yf) yf[ro + c] = o;
    if (yb) yb[ro + c] = f2bf(o);
  }
}

// split-K combine for ff2
__global__ __launch_bounds__(256) void combine_kernel(
    const float* __restrict__ p0, const float* __restrict__ p1,
    const float* __restrict__ bias, const float* __restrict__ res,
    float* __restrict__ yf, short* __restrict__ yb)
{
  const int row = blockIdx.x, tid = threadIdx.x;
  size_t ro = (size_t)row * Dd;
  #pragma unroll
  for (int i = 0; i < 3; ++i) {
    int c = tid + i * 256;
    float v = p0[ro + c] + p1[ro + c] + bias[c] + res[ro + c];
    yf[ro + c] = v;
    yb[ro + c] = f2bf(v);
  }
}

// ---------------- weight convert+transpose: f32 [K][N] -> bf16 [N][K] ----------------
__global__ __launch_bounds__(256) void convT(const float* __restrict__ W, short* __restrict__ Wt,
                                             int K, int N, int ntile)
{
  __shared__ short T[64][72];
  const int bn = blockIdx.x % ntile, bk = blockIdx.x / ntile;
  const int k0 = bk * 64, n0 = bn * 64, tid = threadIdx.x;
  #pragma unroll
  for (int i = 0; i < 4; ++i) {
    int id = i * 256 + tid;
    int r = id >> 4, c4 = (id & 15) * 4;
    float4 w4 = *(const float4*)(W + (size_t)(k0 + r) * N + n0 + c4);
    T[c4 + 0][r] = f2bf(w4.x);
    T[c4 + 1][r] = f2bf(w4.y);
    T[c4 + 2][r] = f2bf(w4.z);
    T[c4 + 3][r] = f2bf(w4.w);
  }
  __syncthreads();
  #pragma unroll
  for (int i = 0; i < 4; ++i) {
    int id = i * 256 + tid;
    int n = id >> 4, k4 = (id & 15) * 4;
    short4v s = *(const short4v*)&T[n][k4];
    *(short4v*)(Wt + (size_t)(n0 + n) * K + k0 + k4) = s;
  }
}

// fused 4x (768x768) weight convert + kv bias concat (block 576)
__global__ __launch_bounds__(256) void convT4(const float* __restrict__ W0, const float* __restrict__ W1,
                                              const float* __restrict__ W2, const float* __restrict__ W3,
                                              const float* __restrict__ bk, const float* __restrict__ bv,
                                              short* __restrict__ Wt, float* __restrict__ kvb)
{
  __shared__ short T[64][72];
  const int tid = threadIdx.x;
  if (blockIdx.x == 576) {
    #pragma unroll
    for (int i = 0; i < 6; ++i) {
      int c = i * 256 + tid;
      if (c < 1536) kvb[c] = (c < 768) ? bk[c] : bv[c - 768];
    }
    return;
  }
  const int wsel = blockIdx.x / 144, rem = blockIdx.x % 144;
  const float* W = wsel == 0 ? W0 : wsel == 1 ? W1 : wsel == 2 ? W2 : W3;
  short* dst = Wt + (size_t)wsel * 768 * 768;
  const int bn = rem % 12, bk2 = rem / 12;
  const int k0 = bk2 * 64, n0 = bn * 64;
  #pragma unroll
  for (int i = 0; i < 4; ++i) {
    int id = i * 256 + tid;
    int r = id >> 4, c4 = (id & 15) * 4;
    float4 w4 = *(const float4*)(W + (size_t)(k0 + r) * 768 + n0 + c4);
    T[c4 + 0][r] = f2bf(w4.x);
    T[c4 + 1][r] = f2bf(w4.y);
    T[c4 + 2][r] = f2bf(w4.z);
    T[c4 + 3][r] = f2bf(w4.w);
  }
  __syncthreads();
  #pragma unroll
  for (int i = 0; i < 4; ++i) {
    int id = i * 256 + tid;
    int n = id >> 4, k4 = (id & 15) * 4;
    short4v s = *(const short4v*)&T[n][k4];
    *(short4v*)(dst + (size_t)(n0 + n) * 768 + k0 + k4) = s;
  }
}

// ---------------- 128x128 bf16 MFMA GEMM (general) ----------------
template<int ACT>
__global__ __launch_bounds__(256) void gemm_bf(
    const short* __restrict__ A, const short* __restrict__ Bt,
    const float* __restrict__ bias, const float* __restrict__ res,
    float* __restrict__ C, short* __restrict__ Cbf, float* __restrict__ Cpart,
    int M, int N, int K, float scale, int mtiles, int ntiles, int ksplit)
{
  __shared__ short As[8192];
  __shared__ short Bs[8192];
  const int tid = threadIdx.x, lane = tid & 63, wv = tid >> 6;
  const int l15 = lane & 15, l4 = lane >> 4;

  const int nwg = gridDim.x;
  const int qc = nwg >> 3, rc = nwg & 7;
  const int xcd = blockIdx.x & 7, idx = blockIdx.x >> 3;
  const int wgid = (xcd < rc ? xcd * (qc + 1) : rc * (qc + 1) + (xcd - rc) * qc) + idx;
  const int by = wgid % mtiles;
  const int rest = wgid / mtiles;
  const int bx = rest % ntiles;
  const int sp = rest / ntiles;
  const int kper = K / ksplit;
  const int kbeg = sp * kper, kend = kbeg + kper;

  const int m0 = by * 128, n0 = bx * 128;
  const int wm = (wv >> 1) * 64, wn = (wv & 1) * 64;
  const int r8 = lane >> 3, c8 = lane & 7;
  const int csw = ((c8 ^ r8) << 3);

  f32x4 acc[4][4];
  const f32x4 zz = {0.f, 0.f, 0.f, 0.f};
  #pragma unroll
  for (int i = 0; i < 4; ++i)
    #pragma unroll
    for (int j = 0; j < 4; ++j) acc[i][j] = zz;

  const short* Ab = A + (size_t)m0 * K + csw;
  const short* Bp = Bt + (size_t)n0 * K + csw;

  for (int k0 = kbeg; k0 < kend; k0 += 64) {
    __syncthreads();
    #pragma unroll
    for (int i = 0; i < 4; ++i) {
      int row = wv * 32 + i * 8 + r8;
      GL16(Ab + (size_t)row * K + k0, &As[(wv * 4 + i) * 512]);
      GL16(Bp + (size_t)row * K + k0, &Bs[(wv * 4 + i) * 512]);
    }
    __syncthreads();
    short8v af[2][4], bfv[2][4];
    #pragma unroll
    for (int kk = 0; kk < 2; ++kk) {
      #pragma unroll
      for (int mi = 0; mi < 4; ++mi)
        af[kk][mi] = *(const short8v*)&As[(wm + mi * 16 + l15) * 64 + ((((kk << 2) | l4) ^ (l15 & 7)) << 3)];
      #pragma unroll
      for (int ni = 0; ni < 4; ++ni)
        bfv[kk][ni] = *(const short8v*)&Bs[(wn + ni * 16 + l15) * 64 + ((((kk << 2) | l4) ^ (l15 & 7)) << 3)];
    }
    #pragma unroll
    for (int kk = 0; kk < 2; ++kk)
      #pragma unroll
      for (int mi = 0; mi < 4; ++mi)
        #pragma unroll
        for (int ni = 0; ni < 4; ++ni)
          acc[mi][ni] = __builtin_amdgcn_mfma_f32_16x16x32_bf16(af[kk][mi], bfv[kk][ni], acc[mi][ni], 0, 0, 0);
  }

  if (Cpart) {
    float* Cp = Cpart + (size_t)sp * M * N;
    #pragma unroll
    for (int mi = 0; mi < 4; ++mi)
      #pragma unroll
      for (int r = 0; r < 4; ++r) {
        int row = m0 + wm + mi * 16 + l4 * 4 + r;
        if (row >= M) continue;
        size_t rb = (size_t)row * N;
        #pragma unroll
        for (int ni = 0; ni < 4; ++ni)
          Cp[rb + n0 + wn + ni * 16 + l15] = acc[mi][ni][r];
      }
    return;
  }

  #pragma unroll
  for (int mi = 0; mi < 4; ++mi) {
    #pragma unroll
    for (int r = 0; r < 4; ++r) {
      int row = m0 + wm + mi * 16 + l4 * 4 + r;
      if (row >= M) continue;
      size_t rb = (size_t)row * N;
      #pragma unroll
      for (int ni = 0; ni < 4; ++ni) {
        int col = n0 + wn + ni * 16 + l15;
        float val = (acc[mi][ni][r] + bias[col]) * scale;
        if (ACT == 1) val = fmaxf(val, 0.f);
        if (ACT == 2) val = gelu_f(val);
        if (res) val += res[rb + col];
        if (C)   C[rb + col] = val;
        if (Cbf) Cbf[rb + col] = f2bf(val);
      }
    }
  }
}

// ---------------- 256x256 / 8-wave / BK=32 double-buffered GEMM (vocab) ----------------
__global__ __launch_bounds__(512, 2) void gemm256(
    const short* __restrict__ A, const short* __restrict__ Bt,
    const float* __restrict__ bias, float* __restrict__ C,
    int M, int N, int K, int mtiles)
{
  __shared__ short As[2][8192];   // [buf][256 rows * 32 k]
  __shared__ short Bs[2][8192];
  const int tid = threadIdx.x, lane = tid & 63, wv = tid >> 6;
  const int l15 = lane & 15, l4 = lane >> 4;

  const int nwg = gridDim.x;
  const int qc = nwg >> 3, rc = nwg & 7;
  const int xcd = blockIdx.x & 7, idx = blockIdx.x >> 3;
  const int wgid = (xcd < rc ? xcd * (qc + 1) : rc * (qc + 1) + (xcd - rc) * qc) + idx;
  const int by = wgid % mtiles, bx = wgid / mtiles;
  const int m0 = by * 256, n0 = bx * 256;
  const int wm = (wv >> 2) * 128, wn = (wv & 3) * 64;

  const int srow = lane >> 2, schunk = lane & 3;
  // linear LDS dest + inverse-swizzled source chunk (rule 21)
  const short* srcA = A + (size_t)(m0 + wv * 32 + srow) * K + ((schunk ^ (srow & 3)) << 3);
  const short* srcB = Bt + (size_t)(n0 + wv * 32 + srow) * K + ((schunk ^ (srow & 3)) << 3);
  const int ldsoff = wv * 1024;   // shorts

  f32x4 acc[8][4];
  const f32x4 zz = {0.f, 0.f, 0.f, 0.f};
  #pragma unroll
  for (int i = 0; i < 8; ++i)
    #pragma unroll
    for (int j = 0; j < 4; ++j) acc[i][j] = zz;

  const int NT = K >> 5;

  GL16(srcA, &As[0][ldsoff]);
  GL16(srcA + (size_t)16 * K, &As[0][ldsoff + 512]);
  GL16(srcB, &Bs[0][ldsoff]);
  GL16(srcB + (size_t)16 * K, &Bs[0][ldsoff + 512]);
  __syncthreads();

  int buf = 0;
  for (int t = 0; t < NT; ++t) {
    if (t + 1 < NT) {
      int k0 = (t + 1) << 5;
      GL16(srcA + k0, &As[buf ^ 1][ldsoff]);
      GL16(srcA + (size_t)16 * K + k0, &As[buf ^ 1][ldsoff + 512]);
      GL16(srcB + k0, &Bs[buf ^ 1][ldsoff]);
      GL16(srcB + (size_t)16 * K + k0, &Bs[buf ^ 1][ldsoff + 512]);
    }
    short8v af[8], bfv[4];
    #pragma unroll
    for (int mi = 0; mi < 8; ++mi)
      af[mi] = *(const short8v*)&As[buf][(wm + mi * 16 + l15) * 32 + ((l4 ^ (l15 & 3)) << 3)];
    #pragma unroll
    for (int ni = 0; ni < 4; ++ni)
      bfv[ni] = *(const short8v*)&Bs[buf][(wn + ni * 16 + l15) * 32 + ((l4 ^ (l15 & 3)) << 3)];
    __builtin_amdgcn_s_setprio(1);
    #pragma unroll
    for (int mi = 0; mi < 8; ++mi)
      #pragma unroll
      for (int ni = 0; ni < 4; ++ni)
        acc[mi][ni] = __builtin_amdgcn_mfma_f32_16x16x32_bf16(af[mi], bfv[ni], acc[mi][ni], 0, 0, 0);
    __builtin_amdgcn_s_setprio(0);
    __syncthreads();
    buf ^= 1;
  }

  #pragma unroll
  for (int mi = 0; mi < 8; ++mi) {
    #pragma unroll
    for (int r = 0; r < 4; ++r) {
      int row = m0 + wm + mi * 16 + l4 * 4 + r;
      size_t rb = (size_t)row * N;
      #pragma unroll
      for (int ni = 0; ni < 4; ++ni) {
        int col = n0 + wn + ni * 16 + l15;
        C[rb + col] = acc[mi][ni][r] + bias[col];
      }
    }
  }
}

// ---------------- flash attention, bf16 in, bf16 out ----------------
__global__ __launch_bounds__(256) void attn_kernel(
    const short* __restrict__ q, const short* __restrict__ kv, short* __restrict__ o)
{
  __shared__ short Kls[64][104];
  __shared__ short Vt[96][72];
  __shared__ short Pls[4][16][72];

  const int tid = threadIdx.x, lane = tid & 63, w = tid >> 6;
  const int l15 = lane & 15, l4 = lane >> 4;
  const int qt = blockIdx.x & 15;
  const int bh = blockIdx.x >> 4;
  const int h = bh & 7, b = bh >> 3;
  const int qb = qt * 64;
  const int qw = qb + w * 16;

  short8v qf[3];
  {
    const short* qp = q + ((size_t)(b * Ss + qw + l15)) * Dd + h * HDh + l4 * 8;
    #pragma unroll
    for (int kk = 0; kk < 3; ++kk) qf[kk] = *(const short8v*)(qp + kk * 32);
  }

  const f32x4 zz = {0.f, 0.f, 0.f, 0.f};
  f32x4 Oa[6];
  #pragma unroll
  for (int fn = 0; fn < 6; ++fn) Oa[fn] = zz;
  float mrow[4], lrow[4];
  #pragma unroll
  for (int r = 0; r < 4; ++r) { mrow[r] = -3.0e38f; lrow[r] = 0.f; }

  const size_t kvbase = (size_t)b * KVr;

  for (int t = 0; t < 33; ++t) {
    int k0 = t * 64;
    bool l2r_vis = (k0 <= Ss) && (k0 - 1 <= qb + 63);
    int rmaxk = (k0 + 63 > 2 * Ss) ? 2 * Ss : (k0 + 63);
    bool r2l_vis = (k0 + 63 >= Ss + 1) && (rmaxk - (Ss + 1) >= qb);
    if (!(t == 0 || l2r_vis || r2l_vis)) continue;

    __syncthreads();
    #pragma unroll
    for (int i = 0; i < 3; ++i) {
      int id = i * 256 + tid;
      int row = id / 12, cc = (id % 12) * 8;
      const short* kp = kv + (kvbase + k0 + row) * 1536 + h * HDh + cc;
      short8v k8 = *(const short8v*)kp;
      *(short8v*)&Kls[row][cc] = k8;
      short8v v8 = *(const short8v*)(kp + 768);
      #pragma unroll
      for (int j = 0; j < 8; ++j) Vt[cc + j][row] = v8[j];
    }
    __syncthreads();

    f32x4 sc[4];
    #pragma unroll
    for (int nt = 0; nt < 4; ++nt) {
      f32x4 d = zz;
      #pragma unroll
      for (int kk = 0; kk < 3; ++kk) {
        short8v kf = *(const short8v*)&Kls[nt * 16 + l15][kk * 32 + l4 * 8];
        d = __builtin_amdgcn_mfma_f32_16x16x32_bf16(qf[kk], kf, d, 0, 0, 0);
      }
      sc[nt] = d;
    }
    float tmax[4] = {-3.0e38f, -3.0e38f, -3.0e38f, -3.0e38f};
    #pragma unroll
    for (int nt = 0; nt < 4; ++nt)
      #pragma unroll
      for (int r = 0; r < 4; ++r) {
        int qg = qw + l4 * 4 + r;
        int j = k0 + nt * 16 + l15;
        bool vis = (j == 0) ||
                   (j >= 1 && j <= Ss && (j - 1) <= qg) ||
                   (j >= Ss + 1 && j <= 2 * Ss && (j - (Ss + 1)) >= qg);
        if (!vis) sc[nt][r] = -3.0e38f;
        tmax[r] = fmaxf(tmax[r], sc[nt][r]);
      }
    #pragma unroll
    for (int r = 0; r < 4; ++r) {
      #pragma unroll
      for (int off = 8; off >= 1; off >>= 1) tmax[r] = fmaxf(tmax[r], __shfl_xor(tmax[r], off));
    }
    float scl[4];
    #pragma unroll
    for (int r = 0; r < 4; ++r) {
      float mnew = fmaxf(mrow[r], tmax[r]);
      scl[r] = __expf(mrow[r] - mnew);
      mrow[r] = mnew;
    }
    #pragma unroll
    for (int fn = 0; fn < 6; ++fn)
      #pragma unroll
      for (int r = 0; r < 4; ++r) Oa[fn][r] *= scl[r];
    float lad[4] = {0.f, 0.f, 0.f, 0.f};
    #pragma unroll
    for (int nt = 0; nt < 4; ++nt)
      #pragma unroll
      for (int r = 0; r < 4; ++r) {
        float p = __expf(sc[nt][r] - mrow[r]);
        lad[r] += p;
        Pls[w][l4 * 4 + r][nt * 16 + l15] = f2bf(p);
      }
    #pragma unroll
    for (int r = 0; r < 4; ++r) {
      #pragma unroll
      for (int off = 8; off >= 1; off >>= 1) lad[r] += __shfl_xor(lad[r], off);
      lrow[r] = lrow[r] * scl[r] + lad[r];
    }
    __syncthreads();

    short8v pf[2];
    #pragma unroll
    for (int kk = 0; kk < 2; ++kk) pf[kk] = *(const short8v*)&Pls[w][l15][kk * 32 + l4 * 8];
    #pragma unroll
    for (int fn = 0; fn < 6; ++fn) {
      #pragma unroll
      for (int kk = 0; kk < 2; ++kk) {
        short8v vf = *(const short8v*)&Vt[fn * 16 + l15][kk * 32 + l4 * 8];
        Oa[fn] = __builtin_amdgcn_mfma_f32_16x16x32_bf16(pf[kk], vf, Oa[fn], 0, 0, 0);
      }
    }
  }

  #pragma unroll
  for (int fn = 0; fn < 6; ++fn)
    #pragma unroll
    for (int r = 0; r < 4; ++r) {
      int row = qw + l4 * 4 + r;
      int col = h * HDh + fn * 16 + l15;
      o[((size_t)(b * Ss + row)) * Dd + col] = f2bf(Oa[fn][r] / lrow[r]);
    }
}

// ---------------- thin (M=2) GEMM, split-K + reduce ----------------
__global__ __launch_bounds__(256) void thin1(const float* __restrict__ A, const float* __restrict__ W,
                                             float* __restrict__ part, int K, int N, int nblk, int splits)
{
  __shared__ float a0s[64], a1s[64];
  const int nb = blockIdx.x % nblk, ks = blockIdx.x / nblk;
  const int kl = K / splits, kbeg = ks * kl;
  const int tid = threadIdx.x;
  for (int k = tid; k < kl; k += 256) { a0s[k] = A[kbeg + k]; a1s[k] = A[K + kbeg + k]; }
  __syncthreads();
  const int n = nb * 256 + tid;
  float acc0 = 0.f, acc1 = 0.f;
  for (int k = 0; k < kl; ++k) {
    float w = W[(size_t)(kbeg + k) * N + n];
    acc0 = fmaf(a0s[k], w, acc0);
    acc1 = fmaf(a1s[k], w, acc1);
  }
  part[(size_t)ks * 2 * N + n] = acc0;
  part[(size_t)ks * 2 * N + N + n] = acc1;
}

template<int ACT>
__global__ __launch_bounds__(256) void thin2(const float* __restrict__ part,
                                             const float* __restrict__ bias,
                                             float* __restrict__ C, int N, int splits)
{
  const int n = blockIdx.x * 256 + threadIdx.x;
  float a0 = bias[n], a1 = a0;
  for (int s = 0; s < splits; ++s) {
    a0 += part[(size_t)s * 2 * N + n];
    a1 += part[(size_t)s * 2 * N + N + n];
  }
  if (ACT == 2) { a0 = gelu_f(a0); a1 = gelu_f(a1); }
  C[n] = a0; C[N + n] = a1;
}

// ---------------- fused FiLM pair (R=2), split-K=64 ----------------
__global__ __launch_bounds__(256) void film1(const float* __restrict__ A,
                                             const float* __restrict__ W,
                                             float* __restrict__ part)
{
  __shared__ float a0s[48], a1s[48];
  const int nb = blockIdx.x % 12, ks = blockIdx.x / 12;
  const int kbeg = ks * 48, tid = threadIdx.x;
  for (int k = tid; k < 48; k += 256) { a0s[k] = A[kbeg + k]; a1s[k] = A[3072 + kbeg + k]; }
  __syncthreads();
  const int n = nb * 256 + tid;        // 0..3071; n<1536 -> film 0, else film 1
  const int col = (n >= 1536) ? (n - 1536) : n;   // 1536 is NOT pow2 — no & trick
  const float* Wp = W + ((n < 1536) ? (size_t)0 : (size_t)3072 * 1536)
                      + (size_t)kbeg * 1536 + col;
  float acc0 = 0.f, acc1 = 0.f;
  for (int k = 0; k < 48; ++k) {
    float w = Wp[(size_t)k * 1536];
    acc0 = fmaf(a0s[k], w, acc0);
    acc1 = fmaf(a1s[k], w, acc1);
  }
  part[(size_t)ks * 6144 + n] = acc0;
  part[(size_t)ks * 6144 + 3072 + n] = acc1;
}

__global__ __launch_bounds__(256) void film2(const float* __restrict__ part,
                                             const float* __restrict__ fb,
                                             float* __restrict__ f0, float* __restrict__ f1)
{
  const int n = blockIdx.x * 256 + threadIdx.x;   // 0..3071
  float a0 = fb[n], a1 = a0;                      // film_b flat [2][1536]
  for (int s = 0; s < 64; ++s) {
    a0 += part[(size_t)s * 6144 + n];
    a1 += part[(size_t)s * 6144 + 3072 + n];
  }
  float* dst = (n < 1536) ? f0 : f1;
  const int c = (n >= 1536) ? (n - 1536) : n;     // 1536 is NOT pow2 — no & trick
  dst[c] = a0;          // batch 0
  dst[1536 + c] = a1;   // batch 1
}

// ---------------- launch helpers ----------------
static void gemm_launch(int act, const short* A, const short* Bt, const float* bias,
                        const float* res, float* C, short* Cbf, float* Cpart,
                        int M, int N, int K, float scale, int ksplit, hipStream_t s)
{
  int mt = (M + 127) >> 7, nt = N >> 7;
  dim3 grid(mt * nt * ksplit), blk(256);
  if (act == 1)      gemm_bf<1><<<grid, blk, 0, s>>>(A, Bt, bias, res, C, Cbf, Cpart, M, N, K, scale, mt, nt, ksplit);
  else if (act == 2) gemm_bf<2><<<grid, blk, 0, s>>>(A, Bt, bias, res, C, Cbf, Cpart, M, N, K, scale, mt, nt, ksplit);
  else               gemm_bf<0><<<grid, blk, 0, s>>>(A, Bt, bias, res, C, Cbf, Cpart, M, N, K, scale, mt, nt, ksplit);
}

static void conv_launch(const float* W, short* Wt, int K, int N, hipStream_t s)
{
  int nt = N >> 6, kt = K >> 6;
  convT<<<dim3(nt * kt), dim3(256), 0, s>>>(W, Wt, K, N, nt);
}

static void thin_launch(int act, const float* A, const float* W, const float* bias,
                        float* C, float* part, int K, int N, hipStream_t s)
{
  int nblk = N >> 8, splits = 64;
  thin1<<<dim3(nblk * splits), dim3(256), 0, s>>>(A, W, part, K, N, nblk, splits);
  if (act == 2) thin2<2><<<dim3(nblk), dim3(256), 0, s>>>(part, bias, C, N, splits);
  else          thin2<0><<<dim3(nblk), dim3(256), 0, s>>>(part, bias, C, N, splits);
}

extern "C" void kernel_launch(void* const* d_in, const int* in_sizes, int n_in,
                              void* d_out, int out_size, void* d_ws, size_t ws_size,
                              hipStream_t stream)
{
  (void)in_sizes; (void)n_in; (void)out_size; (void)ws_size;
  const float* l2r      = (const float*)d_in[0];
  const float* r2l      = (const float*)d_in[1];
  const float* temb     = (const float*)d_in[2];
  const float* ln_l2r_s = (const float*)d_in[3];
  const float* ln_l2r_b = (const float*)d_in[4];
  const float* ln_r2l_s = (const float*)d_in[5];
  const float* ln_r2l_b = (const float*)d_in[6];
  const float* Wq = (const float*)d_in[7];
  const float* bq = (const float*)d_in[8];
  const float* Wk = (const float*)d_in[9];
  const float* bk = (const float*)d_in[10];
  const float* Wv = (const float*)d_in[11];
  const float* bv = (const float*)d_in[12];
  const float* Wo = (const float*)d_in[13];
  const float* bo = (const float*)d_in[14];
  const float* ff_ln_s = (const float*)d_in[15];
  const float* ff_ln_b = (const float*)d_in[16];
  const float* ff_w1 = (const float*)d_in[17];
  const float* ff_b1 = (const float*)d_in[18];
  const float* ff_w2 = (const float*)d_in[19];
  const float* ff_b2 = (const float*)d_in[20];
  const float* tm_w1 = (const float*)d_in[21];
  const float* tm_b1 = (const float*)d_in[22];
  const float* tm_w2 = (const float*)d_in[23];
  const float* tm_b2 = (const float*)d_in[24];
  const float* film_w = (const float*)d_in[25];
  const float* film_b = (const float*)d_in[26];
  const float* r_w1 = (const float*)d_in[27];
  const float* r_b1 = (const float*)d_in[28];
  const float* r_w2 = (const float*)d_in[29];
  const float* r_b2 = (const float*)d_in[30];
  const float* r_ln_s = (const float*)d_in[31];
  const float* r_ln_b = (const float*)d_in[32];
  const float* out_w = (const float*)d_in[33];
  const float* out_b = (const float*)d_in[34];

  uint8_t* base = (uint8_t*)d_ws;
  short* qin_bf  = (short*)(base + 0);
  short* alle_bf = (short*)(base + 3145728);
  short* qb      = (short*)(base + 9440256);
  short* kvbuf   = (short*)(base + 12585984);
  short* attn_bf = (short*)(base + 25175040);
  float* inputs  = (float*)(base + 28320768);
  float* xbuf    = (float*)(base + 34612224);
  short* xn_bf   = (short*)(base + 40903680);
  short* big_bf  = (short*)(base + 44049408);   // 12,582,912
  float* x2f     = (float*)(base + 56632320);
  short* x2bf    = (short*)(base + 62923776);
  float* x3f     = (float*)(base + 72360960);
  short* x3bf    = (short*)(base + 78652416);
  short* x4bf    = (short*)(base + 81798144);
  short* wslot   = (short*)(base + 84943872);
  uint8_t* sm    = base + 89662464;
  float* t1    = (float*)sm;                    // 24,576
  float* tb    = (float*)(sm + 24576);          // 24,576
  float* f0    = (float*)(sm + 49152);          // 12,288
  float* f1    = (float*)(sm + 61440);          // 12,288
  float* kvbia = (float*)(sm + 73728);          // 6,144
  // thin split-K partials (64 x 2 x 3072 f32 = 1.57 MB) alias big_bf (dead during t-path)
  float* part2 = (float*)(base + 44049408);
  // split-K partials for the 768-out K=3072 GEMMs: alias dead early region
  float* partK = (float*)(base + 0);
  short* outwT = (short*)(base + 0);            // 49.15 MB, used only at the end

  const float qscale = 0.1020620726159658f;  // 1/sqrt(96)
  dim3 blk(256);

  // t-path (independent, f32)
  thin_launch(2, temb, tm_w1, tm_b1, t1, part2, 768, 3072, stream);
  thin_launch(0, t1, tm_w2, tm_b2, tb, part2, 3072, 3072, stream);
  film1<<<dim3(12 * 64), blk, 0, stream>>>(tb, film_w, part2);
  film2<<<dim3(12), blk, 0, stream>>>(part2, film_b, f0, f1);

  prep_kernel<<<2050, blk, 0, stream>>>(l2r, r2l, temb, ln_l2r_s, ln_l2r_b, ln_r2l_s, ln_r2l_b,
                                        inputs, qin_bf, alle_bf);

  convT4<<<dim3(577), blk, 0, stream>>>(Wq, Wk, Wv, Wo, bk, bv, wslot, kvbia);

  gemm_launch(0, qin_bf, wslot, bq, nullptr, nullptr, qb, nullptr, 2048, 768, 768, qscale, 1, stream);
  gemm_launch(0, alle_bf, wslot + (size_t)768 * 768, kvbia, nullptr, nullptr, kvbuf, nullptr, 4098, 1536, 768, 1.f, 1, stream);

  attn_kernel<<<256, blk, 0, stream>>>(qb, kvbuf, attn_bf);

  gemm_launch(0, attn_bf, wslot + (size_t)3 * 768 * 768, bo, inputs, xbuf, nullptr, nullptr, 2048, 768, 768, 1.f, 1, stream);
  ln_kernel<<<2048, blk, 0, stream>>>(xbuf, ff_ln_s, ff_ln_b, xn_bf);

  conv_launch(ff_w1, wslot, 768, 3072, stream);
  gemm_launch(1, xn_bf, wslot, ff_b1, nullptr, nullptr, big_bf, nullptr, 2048, 3072, 768, 1.f, 1, stream);
  conv_launch(ff_w2, wslot, 3072, 768, stream);
  gemm_launch(0, big_bf, wslot, nullptr, nullptr, nullptr, nullptr, partK, 2048, 768, 3072, 1.f, 2, stream);
  combine_kernel<<<2048, blk, 0, stream>>>(partK, partK + (size_t)2048 * 768, ff_b2, xbuf, x2f, x2bf);

  // residual block 0
  conv_launch(r_w1, wslot, 768, 3072, stream);
  gemm_launch(2, x2bf, wslot, r_b1, nullptr, nullptr, big_bf, nullptr, 2048, 3072, 768, 1.f, 1, stream);
  conv_launch(r_w2, wslot, 3072, 768, stream);
  gemm_launch(0, big_bf, wslot, nullptr, nullptr, nullptr, nullptr, partK, 2048, 768, 3072, 1.f, 2, stream);
  ln_comb<<<2048, blk, 0, stream>>>(partK, partK + (size_t)2048 * 768, r_b2, x2f,
                                    r_ln_s, r_ln_b, f0, x3f, x3bf);

  // residual block 1
  conv_launch(r_w1 + (size_t)768 * 3072, wslot, 768, 3072, stream);
  gemm_launch(2, x3bf, wslot, r_b1 + 3072, nullptr, nullptr, big_bf, nullptr, 2048, 3072, 768, 1.f, 1, stream);
  conv_launch(r_w2 + (size_t)3072 * 768, wslot, 3072, 768, stream);
  gemm_launch(0, big_bf, wslot, nullptr, nullptr, nullptr, nullptr, partK, 2048, 768, 3072, 1.f, 2, stream);
  ln_comb<<<2048, blk, 0, stream>>>(partK, partK + (size_t)2048 * 768, r_b2 + 768, x3f,
                                    r_ln_s + 768, r_ln_b + 768, f1, nullptr, x4bf);

  // vocab projection: convert out_w, then 256^2 double-buffered GEMM
  conv_launch(out_w, outwT, 768, 32000, stream);
  gemm256<<<dim3(8 * 125), dim3(512), 0, stream>>>(x4bf, outwT, out_b, (float*)d_out,
                                                   2048, 32000, 768, 8);
}

// Round 6
// 642.429 us; speedup vs baseline: 3.3943x; 1.0790x over previous
//
#include <hip/hip_runtime.h>
#include <cstdint>
#include <cstddef>

#define Bb 2
#define Ss 1024
#define Dd 768
#define Hh 8
#define HDh 96
#define Mm 3072
#define Vv 32000
#define KVr 2049   // 2S+1

typedef __attribute__((ext_vector_type(8))) short short8v;
typedef __attribute__((ext_vector_type(4))) short short4v;
typedef __attribute__((ext_vector_type(4))) float f32x4;

#define GL16(gp, lp) __builtin_amdgcn_global_load_lds( \
    (const __attribute__((address_space(1))) void*)(gp), \
    (__attribute__((address_space(3))) void*)(lp), 16, 0, 0)

static __device__ __forceinline__ short f2bf(float f) {
  union { float f; unsigned u; } x; x.f = f;
  unsigned r = (x.u + 0x7FFFu + ((x.u >> 16) & 1u)) >> 16;  // RNE
  return (short)(r & 0xFFFFu);
}

static __device__ __forceinline__ float gelu_f(float v) {
  float u = 0.7978845608028654f * (v + 0.044715f * v * v * v);
  float au = fabsf(u);
  float e = __expf(2.f * au);
  float t = 1.f - 2.f / (e + 1.f);     // tanh(|u|), safe at inf
  return 0.5f * v * (1.f + copysignf(t, u));
}

static __device__ __forceinline__ float blk_sum(float val, float* sh) {
  #pragma unroll
  for (int off = 32; off >= 1; off >>= 1) val += __shfl_xor(val, off);
  __syncthreads();
  if ((threadIdx.x & 63) == 0) sh[threadIdx.x >> 6] = val;
  __syncthreads();
  return sh[0] + sh[1] + sh[2] + sh[3];
}

// ---------------- prep: inputs(f32), qin(bf16), all_e rows (bf16), temb rows ----------------
__global__ __launch_bounds__(256) void prep_kernel(
    const float* __restrict__ l2r, const float* __restrict__ r2l,
    const float* __restrict__ temb,
    const float* __restrict__ s1, const float* __restrict__ b1,
    const float* __restrict__ s2, const float* __restrict__ b2,
    float* __restrict__ inputs, short* __restrict__ qin, short* __restrict__ all_e)
{
  __shared__ float sh[4];
  const int tid = threadIdx.x;
  if (blockIdx.x >= 2048) {   // temb rows of all_e
    int b = blockIdx.x - 2048;
    #pragma unroll
    for (int i = 0; i < 3; ++i)
      all_e[(size_t)b * KVr * Dd + tid + i * 256] = f2bf(temb[(size_t)b * Dd + tid + i * 256]);
    return;
  }
  const int row = blockIdx.x;
  const int b = row >> 10, s = row & 1023;
  const float* ap = l2r + (size_t)row * Dd;
  const float* cp = r2l + (size_t)row * Dd;
  float a0 = ap[tid], a1 = ap[tid + 256], a2 = ap[tid + 512];
  float c0 = cp[tid], c1 = cp[tid + 256], c2 = cp[tid + 512];
  float ma = blk_sum(a0 + a1 + a2, sh) * (1.f / 768.f);
  float mc = blk_sum(c0 + c1 + c2, sh) * (1.f / 768.f);
  float va = blk_sum((a0-ma)*(a0-ma) + (a1-ma)*(a1-ma) + (a2-ma)*(a2-ma), sh) * (1.f / 768.f);
  float vc = blk_sum((c0-mc)*(c0-mc) + (c1-mc)*(c1-mc) + (c2-mc)*(c2-mc), sh) * (1.f / 768.f);
  float ia = rsqrtf(va + 1e-6f), ic = rsqrtf(vc + 1e-6f);
  size_t ro = (size_t)row * Dd;
  size_t e1 = ((size_t)b * KVr + 1 + s) * Dd;
  size_t e2 = ((size_t)b * KVr + 1 + Ss + s) * Dd;
  float av[3] = {a0, a1, a2}, cv[3] = {c0, c1, c2};
  #pragma unroll
  for (int i = 0; i < 3; ++i) {
    int c = tid + i * 256;
    float an = (av[i] - ma) * ia * s1[c] + b1[c];
    float cn = (cv[i] - mc) * ic * s2[c] + b2[c];
    inputs[ro + c] = av[i] + cv[i];
    qin[ro + c]    = f2bf(an + cn);
    all_e[e1 + c]  = f2bf(an);
    all_e[e2 + c]  = f2bf(cn);
  }
}

// ---------------- LayerNorm (plain, bf16 out) ----------------
__global__ __launch_bounds__(256) void ln_kernel(
    const float* __restrict__ x, const float* __restrict__ sc, const float* __restrict__ bi,
    short* __restrict__ yb)
{
  __shared__ float sh[4];
  const int row = blockIdx.x, tid = threadIdx.x;
  const float* xr = x + (size_t)row * Dd;
  float v0 = xr[tid], v1 = xr[tid + 256], v2 = xr[tid + 512];
  float m = blk_sum(v0 + v1 + v2, sh) * (1.f / 768.f);
  float var = blk_sum((v0-m)*(v0-m) + (v1-m)*(v1-m) + (v2-m)*(v2-m), sh) * (1.f / 768.f);
  float inv = rsqrtf(var + 1e-6f);
  float vv[3] = {v0, v1, v2};
  #pragma unroll
  for (int i = 0; i < 3; ++i) {
    int c = tid + i * 256;
    yb[(size_t)row * Dd + c] = f2bf((vv[i] - m) * inv * sc[c] + bi[c]);
  }
}

// ---------------- split-K(4) combine + LN + FiLM ----------------
__global__ __launch_bounds__(256) void ln_comb(
    const float* __restrict__ pk,
    const float* __restrict__ bias, const float* __restrict__ res,
    const float* __restrict__ sc, const float* __restrict__ bi,
    const float* __restrict__ film, float* __restrict__ yf, short* __restrict__ yb)
{
  __shared__ float sh[4];
  const int row = blockIdx.x, tid = threadIdx.x;
  const size_t PS = (size_t)2048 * 768;
  size_t ro = (size_t)row * Dd;
  float vv[3];
  #pragma unroll
  for (int i = 0; i < 3; ++i) {
    int c = tid + i * 256;
    float v = bias[c] + res[ro + c];
    #pragma unroll
    for (int s = 0; s < 4; ++s) v += pk[s * PS + ro + c];
    vv[i] = v;
  }
  float m = blk_sum(vv[0] + vv[1] + vv[2], sh) * (1.f / 768.f);
  float var = blk_sum((vv[0]-m)*(vv[0]-m) + (vv[1]-m)*(vv[1]-m) + (vv[2]-m)*(vv[2]-m), sh) * (1.f / 768.f);
  float inv = rsqrtf(var + 1e-6f);
  int bb = row >> 10;
  #pragma unroll
  for (int i = 0; i < 3; ++i) {
    int c = tid + i * 256;
    float o = (vv[i] - m) * inv * sc[c] + bi[c];
    o = film[(size_t)bb * 1536 + c] * o + film[(size_t)bb * 1536 + 768 + c];
    if (yf) yf[ro + c] = o;
    if (yb) yb[ro + c] = f2bf(o);
  }
}

// split-K(4) combine for ff2
__global__ __launch_bounds__(256) void combine_kernel(
    const float* __restrict__ pk,
    const float* __restrict__ bias, const float* __restrict__ res,
    float* __restrict__ yf, short* __restrict__ yb)
{
  const int row = blockIdx.x, tid = threadIdx.x;
  const size_t PS = (size_t)2048 * 768;
  size_t ro = (size_t)row * Dd;
  #pragma unroll
  for (int i = 0; i < 3; ++i) {
    int c = tid + i * 256;
    float v = bias[c] + res[ro + c];
    #pragma unroll
    for (int s = 0; s < 4; ++s) v += pk[s * PS + ro + c];
    yf[ro + c] = v;
    yb[ro + c] = f2bf(v);
  }
}

// ---------------- weight convert+transpose: f32 [K][N] -> bf16 [N][K] ----------------
__global__ __launch_bounds__(256) void convT(const float* __restrict__ W, short* __restrict__ Wt,
                                             int K, int N, int ntile)
{
  __shared__ short T[64][72];
  const int bn = blockIdx.x % ntile, bk = blockIdx.x / ntile;
  const int k0 = bk * 64, n0 = bn * 64, tid = threadIdx.x;
  #pragma unroll
  for (int i = 0; i < 4; ++i) {
    int id = i * 256 + tid;
    int r = id >> 4, c4 = (id & 15) * 4;
    float4 w4 = *(const float4*)(W + (size_t)(k0 + r) * N + n0 + c4);
    T[c4 + 0][r] = f2bf(w4.x);
    T[c4 + 1][r] = f2bf(w4.y);
    T[c4 + 2][r] = f2bf(w4.z);
    T[c4 + 3][r] = f2bf(w4.w);
  }
  __syncthreads();
  #pragma unroll
  for (int i = 0; i < 4; ++i) {
    int id = i * 256 + tid;
    int n = id >> 4, k4 = (id & 15) * 4;
    short4v s = *(const short4v*)&T[n][k4];
    *(short4v*)(Wt + (size_t)(n0 + n) * K + k0 + k4) = s;
  }
}

// fused 4x (768x768) weight convert + kv bias concat (block 576)
__global__ __launch_bounds__(256) void convT4(const float* __restrict__ W0, const float* __restrict__ W1,
                                              const float* __restrict__ W2, const float* __restrict__ W3,
                                              const float* __restrict__ bk, const float* __restrict__ bv,
                                              short* __restrict__ Wt, float* __restrict__ kvb)
{
  __shared__ short T[64][72];
  const int tid = threadIdx.x;
  if (blockIdx.x == 576) {
    #pragma unroll
    for (int i = 0; i < 6; ++i) {
      int c = i * 256 + tid;
      if (c < 1536) kvb[c] = (c < 768) ? bk[c] : bv[c - 768];
    }
    return;
  }
  const int wsel = blockIdx.x / 144, rem = blockIdx.x % 144;
  const float* W = wsel == 0 ? W0 : wsel == 1 ? W1 : wsel == 2 ? W2 : W3;
  short* dst = Wt + (size_t)wsel * 768 * 768;
  const int bn = rem % 12, bk2 = rem / 12;
  const int k0 = bk2 * 64, n0 = bn * 64;
  #pragma unroll
  for (int i = 0; i < 4; ++i) {
    int id = i * 256 + tid;
    int r = id >> 4, c4 = (id & 15) * 4;
    float4 w4 = *(const float4*)(W + (size_t)(k0 + r) * 768 + n0 + c4);
    T[c4 + 0][r] = f2bf(w4.x);
    T[c4 + 1][r] = f2bf(w4.y);
    T[c4 + 2][r] = f2bf(w4.z);
    T[c4 + 3][r] = f2bf(w4.w);
  }
  __syncthreads();
  #pragma unroll
  for (int i = 0; i < 4; ++i) {
    int id = i * 256 + tid;
    int n = id >> 4, k4 = (id & 15) * 4;
    short4v s = *(const short4v*)&T[n][k4];
    *(short4v*)(dst + (size_t)(n0 + n) * 768 + k0 + k4) = s;
  }
}

// ---------------- 128x128 bf16 MFMA GEMM, dbuf + counted vmcnt ----------------
template<int ACT>
__global__ __launch_bounds__(256) void gemm_bf(
    const short* __restrict__ A, const short* __restrict__ Bt,
    const float* __restrict__ bias, const float* __restrict__ res,
    float* __restrict__ C, short* __restrict__ Cbf, float* __restrict__ Cpart,
    int M, int N, int K, float scale, int mtiles, int ntiles, int ksplit)
{
  __shared__ short As[2][8192];
  __shared__ short Bs[2][8192];
  const int tid = threadIdx.x, lane = tid & 63, wv = tid >> 6;
  const int l15 = lane & 15, l4 = lane >> 4;

  const int nwg = gridDim.x;
  const int qc = nwg >> 3, rc = nwg & 7;
  const int xcd = blockIdx.x & 7, idx = blockIdx.x >> 3;
  const int wgid = (xcd < rc ? xcd * (qc + 1) : rc * (qc + 1) + (xcd - rc) * qc) + idx;
  const int by = wgid % mtiles;
  const int rest = wgid / mtiles;
  const int bx = rest % ntiles;
  const int sp = rest / ntiles;
  const int kper = K / ksplit;
  const int kbeg = sp * kper;
  const int NT = kper >> 6;

  const int m0 = by * 128, n0 = bx * 128;
  const int wm = (wv >> 1) * 64, wn = (wv & 1) * 64;
  const int r8 = lane >> 3, c8 = lane & 7;
  const int csw = ((c8 ^ r8) << 3);

  f32x4 acc[4][4];
  const f32x4 zz = {0.f, 0.f, 0.f, 0.f};
  #pragma unroll
  for (int i = 0; i < 4; ++i)
    #pragma unroll
    for (int j = 0; j < 4; ++j) acc[i][j] = zz;

  const short* Ab = A + (size_t)m0 * K + kbeg + csw;
  const short* Bp = Bt + (size_t)n0 * K + kbeg + csw;

  // prologue: stage tile 0 -> buf 0
  #pragma unroll
  for (int i = 0; i < 4; ++i) {
    int row = wv * 32 + i * 8 + r8;
    GL16(Ab + (size_t)row * K, &As[0][(wv * 4 + i) * 512]);
    GL16(Bp + (size_t)row * K, &Bs[0][(wv * 4 + i) * 512]);
  }

  int buf = 0;
  for (int t = 0; t < NT; ++t) {
    if (t + 1 < NT) {
      int k0 = (t + 1) << 6;
      #pragma unroll
      for (int i = 0; i < 4; ++i) {
        int row = wv * 32 + i * 8 + r8;
        GL16(Ab + (size_t)row * K + k0, &As[buf ^ 1][(wv * 4 + i) * 512]);
        GL16(Bp + (size_t)row * K + k0, &Bs[buf ^ 1][(wv * 4 + i) * 512]);
      }
      asm volatile("s_waitcnt vmcnt(8)" ::: "memory");   // prev tile landed; 8 new in flight
    } else {
      asm volatile("s_waitcnt vmcnt(0)" ::: "memory");
    }
    __builtin_amdgcn_s_barrier();

    short8v af[2][4], bfv[2][4];
    #pragma unroll
    for (int kk = 0; kk < 2; ++kk) {
      #pragma unroll
      for (int mi = 0; mi < 4; ++mi)
        af[kk][mi] = *(const short8v*)&As[buf][(wm + mi * 16 + l15) * 64 + ((((kk << 2) | l4) ^ (l15 & 7)) << 3)];
      #pragma unroll
      for (int ni = 0; ni < 4; ++ni)
        bfv[kk][ni] = *(const short8v*)&Bs[buf][(wn + ni * 16 + l15) * 64 + ((((kk << 2) | l4) ^ (l15 & 7)) << 3)];
    }
    __builtin_amdgcn_s_setprio(1);
    #pragma unroll
    for (int kk = 0; kk < 2; ++kk)
      #pragma unroll
      for (int mi = 0; mi < 4; ++mi)
        #pragma unroll
        for (int ni = 0; ni < 4; ++ni)
          acc[mi][ni] = __builtin_amdgcn_mfma_f32_16x16x32_bf16(af[kk][mi], bfv[kk][ni], acc[mi][ni], 0, 0, 0);
    __builtin_amdgcn_s_setprio(0);
    if (t + 1 < NT) __builtin_amdgcn_s_barrier();   // reads done before next restage
    buf ^= 1;
  }

  if (Cpart) {
    float* Cp = Cpart + (size_t)sp * M * N;
    #pragma unroll
    for (int mi = 0; mi < 4; ++mi)
      #pragma unroll
      for (int r = 0; r < 4; ++r) {
        int row = m0 + wm + mi * 16 + l4 * 4 + r;
        if (row >= M) continue;
        size_t rb = (size_t)row * N;
        #pragma unroll
        for (int ni = 0; ni < 4; ++ni)
          Cp[rb + n0 + wn + ni * 16 + l15] = acc[mi][ni][r];
      }
    return;
  }

  #pragma unroll
  for (int mi = 0; mi < 4; ++mi) {
    #pragma unroll
    for (int r = 0; r < 4; ++r) {
      int row = m0 + wm + mi * 16 + l4 * 4 + r;
      if (row >= M) continue;
      size_t rb = (size_t)row * N;
      #pragma unroll
      for (int ni = 0; ni < 4; ++ni) {
        int col = n0 + wn + ni * 16 + l15;
        float val = (acc[mi][ni][r] + bias[col]) * scale;
        if (ACT == 1) val = fmaxf(val, 0.f);
        if (ACT == 2) val = gelu_f(val);
        if (res) val += res[rb + col];
        if (C)   C[rb + col] = val;
        if (Cbf) Cbf[rb + col] = f2bf(val);
      }
    }
  }
}

// ---------------- 256x256 / 8-wave / BK=32 dbuf + counted vmcnt (vocab) ----------------
__global__ __launch_bounds__(512, 2) void gemm256(
    const short* __restrict__ A, const short* __restrict__ Bt,
    const float* __restrict__ bias, float* __restrict__ C,
    int M, int N, int K, int mtiles)
{
  __shared__ short As[2][8192];   // [buf][256 rows * 32 k], rows 64 B
  __shared__ short Bs[2][8192];
  const int tid = threadIdx.x, lane = tid & 63, wv = tid >> 6;
  const int l15 = lane & 15, l4 = lane >> 4;

  const int nwg = gridDim.x;
  const int qc = nwg >> 3, rc = nwg & 7;
  const int xcd = blockIdx.x & 7, idx = blockIdx.x >> 3;
  const int wgid = (xcd < rc ? xcd * (qc + 1) : rc * (qc + 1) + (xcd - rc) * qc) + idx;
  const int by = wgid % mtiles, bx = wgid / mtiles;
  const int m0 = by * 256, n0 = bx * 256;
  const int wm = (wv >> 2) * 128, wn = (wv & 3) * 64;

  // staging: 16 rows x 4 chunks per GL16; swizzle chunk by (row>>1)&3 (2-way max)
  const int srow = lane >> 2, schunk = lane & 3;
  const short* srcA = A + (size_t)(m0 + wv * 32 + srow) * K + ((schunk ^ ((srow >> 1) & 3)) << 3);
  const short* srcB = Bt + (size_t)(n0 + wv * 32 + srow) * K + ((schunk ^ ((srow >> 1) & 3)) << 3);
  const int ldsoff = wv * 1024;   // shorts

  f32x4 acc[8][4];
  const f32x4 zz = {0.f, 0.f, 0.f, 0.f};
  #pragma unroll
  for (int i = 0; i < 8; ++i)
    #pragma unroll
    for (int j = 0; j < 4; ++j) acc[i][j] = zz;

  const int NT = K >> 5;
  const int rsw = (l15 >> 1) & 3;

  // prologue
  GL16(srcA, &As[0][ldsoff]);
  GL16(srcA + (size_t)16 * K, &As[0][ldsoff + 512]);
  GL16(srcB, &Bs[0][ldsoff]);
  GL16(srcB + (size_t)16 * K, &Bs[0][ldsoff + 512]);

  int buf = 0;
  for (int t = 0; t < NT; ++t) {
    if (t + 1 < NT) {
      int k0 = (t + 1) << 5;
      GL16(srcA + k0, &As[buf ^ 1][ldsoff]);
      GL16(srcA + (size_t)16 * K + k0, &As[buf ^ 1][ldsoff + 512]);
      GL16(srcB + k0, &Bs[buf ^ 1][ldsoff]);
      GL16(srcB + (size_t)16 * K + k0, &Bs[buf ^ 1][ldsoff + 512]);
      asm volatile("s_waitcnt vmcnt(4)" ::: "memory");
    } else {
      asm volatile("s_waitcnt vmcnt(0)" ::: "memory");
    }
    __builtin_amdgcn_s_barrier();

    short8v af[8], bfv[4];
    #pragma unroll
    for (int mi = 0; mi < 8; ++mi)
      af[mi] = *(const short8v*)&As[buf][(wm + mi * 16 + l15) * 32 + ((l4 ^ rsw) << 3)];
    #pragma unroll
    for (int ni = 0; ni < 4; ++ni)
      bfv[ni] = *(const short8v*)&Bs[buf][(wn + ni * 16 + l15) * 32 + ((l4 ^ rsw) << 3)];
    __builtin_amdgcn_s_setprio(1);
    #pragma unroll
    for (int mi = 0; mi < 8; ++mi)
      #pragma unroll
      for (int ni = 0; ni < 4; ++ni)
        acc[mi][ni] = __builtin_amdgcn_mfma_f32_16x16x32_bf16(af[mi], bfv[ni], acc[mi][ni], 0, 0, 0);
    __builtin_amdgcn_s_setprio(0);
    if (t + 1 < NT) __builtin_amdgcn_s_barrier();
    buf ^= 1;
  }

  #pragma unroll
  for (int mi = 0; mi < 8; ++mi) {
    #pragma unroll
    for (int r = 0; r < 4; ++r) {
      int row = m0 + wm + mi * 16 + l4 * 4 + r;
      size_t rb = (size_t)row * N;
      #pragma unroll
      for (int ni = 0; ni < 4; ++ni) {
        int col = n0 + wn + ni * 16 + l15;
        C[rb + col] = acc[mi][ni][r] + bias[col];
      }
    }
  }
}

// ---------------- flash attention, bf16 in, bf16 out ----------------
__global__ __launch_bounds__(256) void attn_kernel(
    const short* __restrict__ q, const short* __restrict__ kv, short* __restrict__ o)
{
  __shared__ short Kls[64][104];
  __shared__ short Vt[96][72];
  __shared__ short Pls[4][16][72];

  const int tid = threadIdx.x, lane = tid & 63, w = tid >> 6;
  const int l15 = lane & 15, l4 = lane >> 4;
  const int qt = blockIdx.x & 15;
  const int bh = blockIdx.x >> 4;
  const int h = bh & 7, b = bh >> 3;
  const int qb = qt * 64;
  const int qw = qb + w * 16;

  short8v qf[3];
  {
    const short* qp = q + ((size_t)(b * Ss + qw + l15)) * Dd + h * HDh + l4 * 8;
    #pragma unroll
    for (int kk = 0; kk < 3; ++kk) qf[kk] = *(const short8v*)(qp + kk * 32);
  }

  const f32x4 zz = {0.f, 0.f, 0.f, 0.f};
  f32x4 Oa[6];
  #pragma unroll
  for (int fn = 0; fn < 6; ++fn) Oa[fn] = zz;
  float mrow[4], lrow[4];
  #pragma unroll
  for (int r = 0; r < 4; ++r) { mrow[r] = -3.0e38f; lrow[r] = 0.f; }

  const size_t kvbase = (size_t)b * KVr;

  for (int t = 0; t < 33; ++t) {
    int k0 = t * 64;
    bool l2r_vis = (k0 <= Ss) && (k0 - 1 <= qb + 63);
    int rmaxk = (k0 + 63 > 2 * Ss) ? 2 * Ss : (k0 + 63);
    bool r2l_vis = (k0 + 63 >= Ss + 1) && (rmaxk - (Ss + 1) >= qb);
    if (!(t == 0 || l2r_vis || r2l_vis)) continue;

    __syncthreads();
    #pragma unroll
    for (int i = 0; i < 3; ++i) {
      int id = i * 256 + tid;
      int row = id / 12, cc = (id % 12) * 8;
      const short* kp = kv + (kvbase + k0 + row) * 1536 + h * HDh + cc;
      short8v k8 = *(const short8v*)kp;
      *(short8v*)&Kls[row][cc] = k8;
      short8v v8 = *(const short8v*)(kp + 768);
      #pragma unroll
      for (int j = 0; j < 8; ++j) Vt[cc + j][row] = v8[j];
    }
    __syncthreads();

    f32x4 sc[4];
    #pragma unroll
    for (int nt = 0; nt < 4; ++nt) {
      f32x4 d = zz;
      #pragma unroll
      for (int kk = 0; kk < 3; ++kk) {
        short8v kf = *(const short8v*)&Kls[nt * 16 + l15][kk * 32 + l4 * 8];
        d = __builtin_amdgcn_mfma_f32_16x16x32_bf16(qf[kk], kf, d, 0, 0, 0);
      }
      sc[nt] = d;
    }
    float tmax[4] = {-3.0e38f, -3.0e38f, -3.0e38f, -3.0e38f};
    #pragma unroll
    for (int nt = 0; nt < 4; ++nt)
      #pragma unroll
      for (int r = 0; r < 4; ++r) {
        int qg = qw + l4 * 4 + r;
        int j = k0 + nt * 16 + l15;
        bool vis = (j == 0) ||
                   (j >= 1 && j <= Ss && (j - 1) <= qg) ||
                   (j >= Ss + 1 && j <= 2 * Ss && (j - (Ss + 1)) >= qg);
        if (!vis) sc[nt][r] = -3.0e38f;
        tmax[r] = fmaxf(tmax[r], sc[nt][r]);
      }
    #pragma unroll
    for (int r = 0; r < 4; ++r) {
      #pragma unroll
      for (int off = 8; off >= 1; off >>= 1) tmax[r] = fmaxf(tmax[r], __shfl_xor(tmax[r], off));
    }
    float scl[4];
    #pragma unroll
    for (int r = 0; r < 4; ++r) {
      float mnew = fmaxf(mrow[r], tmax[r]);
      scl[r] = __expf(mrow[r] - mnew);
      mrow[r] = mnew;
    }
    #pragma unroll
    for (int fn = 0; fn < 6; ++fn)
      #pragma unroll
      for (int r = 0; r < 4; ++r) Oa[fn][r] *= scl[r];
    float lad[4] = {0.f, 0.f, 0.f, 0.f};
    #pragma unroll
    for (int nt = 0; nt < 4; ++nt)
      #pragma unroll
      for (int r = 0; r < 4; ++r) {
        float p = __expf(sc[nt][r] - mrow[r]);
        lad[r] += p;
        Pls[w][l4 * 4 + r][nt * 16 + l15] = f2bf(p);
      }
    #pragma unroll
    for (int r = 0; r < 4; ++r) {
      #pragma unroll
      for (int off = 8; off >= 1; off >>= 1) lad[r] += __shfl_xor(lad[r], off);
      lrow[r] = lrow[r] * scl[r] + lad[r];
    }
    __syncthreads();

    short8v pf[2];
    #pragma unroll
    for (int kk = 0; kk < 2; ++kk) pf[kk] = *(const short8v*)&Pls[w][l15][kk * 32 + l4 * 8];
    #pragma unroll
    for (int fn = 0; fn < 6; ++fn) {
      #pragma unroll
      for (int kk = 0; kk < 2; ++kk) {
        short8v vf = *(const short8v*)&Vt[fn * 16 + l15][kk * 32 + l4 * 8];
        Oa[fn] = __builtin_amdgcn_mfma_f32_16x16x32_bf16(pf[kk], vf, Oa[fn], 0, 0, 0);
      }
    }
  }

  #pragma unroll
  for (int fn = 0; fn < 6; ++fn)
    #pragma unroll
    for (int r = 0; r < 4; ++r) {
      int row = qw + l4 * 4 + r;
      int col = h * HDh + fn * 16 + l15;
      o[((size_t)(b * Ss + row)) * Dd + col] = f2bf(Oa[fn][r] / lrow[r]);
    }
}

// ---------------- thin (M=2) GEMM, split-K + reduce ----------------
__global__ __launch_bounds__(256) void thin1(const float* __restrict__ A, const float* __restrict__ W,
                                             float* __restrict__ part, int K, int N, int nblk, int splits)
{
  __shared__ float a0s[64], a1s[64];
  const int nb = blockIdx.x % nblk, ks = blockIdx.x / nblk;
  const int kl = K / splits, kbeg = ks * kl;
  const int tid = threadIdx.x;
  for (int k = tid; k < kl; k += 256) { a0s[k] = A[kbeg + k]; a1s[k] = A[K + kbeg + k]; }
  __syncthreads();
  const int n = nb * 256 + tid;
  float acc0 = 0.f, acc1 = 0.f;
  for (int k = 0; k < kl; ++k) {
    float w = W[(size_t)(kbeg + k) * N + n];
    acc0 = fmaf(a0s[k], w, acc0);
    acc1 = fmaf(a1s[k], w, acc1);
  }
  part[(size_t)ks * 2 * N + n] = acc0;
  part[(size_t)ks * 2 * N + N + n] = acc1;
}

template<int ACT>
__global__ __launch_bounds__(256) void thin2(const float* __restrict__ part,
                                             const float* __restrict__ bias,
                                             float* __restrict__ C, int N, int splits)
{
  const int n = blockIdx.x * 256 + threadIdx.x;
  float a0 = bias[n], a1 = a0;
  for (int s = 0; s < splits; ++s) {
    a0 += part[(size_t)s * 2 * N + n];
    a1 += part[(size_t)s * 2 * N + N + n];
  }
  if (ACT == 2) { a0 = gelu_f(a0); a1 = gelu_f(a1); }
  C[n] = a0; C[N + n] = a1;
}

// ---------------- fused FiLM pair (R=2), split-K=64 ----------------
__global__ __launch_bounds__(256) void film1(const float* __restrict__ A,
                                             const float* __restrict__ W,
                                             float* __restrict__ part)
{
  __shared__ float a0s[48], a1s[48];
  const int nb = blockIdx.x % 12, ks = blockIdx.x / 12;
  const int kbeg = ks * 48, tid = threadIdx.x;
  for (int k = tid; k < 48; k += 256) { a0s[k] = A[kbeg + k]; a1s[k] = A[3072 + kbeg + k]; }
  __syncthreads();
  const int n = nb * 256 + tid;        // 0..3071; n<1536 -> film 0, else film 1
  const int col = (n >= 1536) ? (n - 1536) : n;   // 1536 is NOT pow2
  const float* Wp = W + ((n < 1536) ? (size_t)0 : (size_t)3072 * 1536)
                      + (size_t)kbeg * 1536 + col;
  float acc0 = 0.f, acc1 = 0.f;
  for (int k = 0; k < 48; ++k) {
    float w = Wp[(size_t)k * 1536];
    acc0 = fmaf(a0s[k], w, acc0);
    acc1 = fmaf(a1s[k], w, acc1);
  }
  part[(size_t)ks * 6144 + n] = acc0;
  part[(size_t)ks * 6144 + 3072 + n] = acc1;
}

__global__ __launch_bounds__(256) void film2(const float* __restrict__ part,
                                             const float* __restrict__ fb,
                                             float* __restrict__ f0, float* __restrict__ f1)
{
  const int n = blockIdx.x * 256 + threadIdx.x;   // 0..3071
  float a0 = fb[n], a1 = a0;                      // film_b flat [2][1536]
  for (int s = 0; s < 64; ++s) {
    a0 += part[(size_t)s * 6144 + n];
    a1 += part[(size_t)s * 6144 + 3072 + n];
  }
  float* dst = (n < 1536) ? f0 : f1;
  const int c = (n >= 1536) ? (n - 1536) : n;
  dst[c] = a0;          // batch 0
  dst[1536 + c] = a1;   // batch 1
}

// ---------------- launch helpers ----------------
static void gemm_launch(int act, const short* A, const short* Bt, const float* bias,
                        const float* res, float* C, short* Cbf, float* Cpart,
                        int M, int N, int K, float scale, int ksplit, hipStream_t s)
{
  int mt = (M + 127) >> 7, nt = N >> 7;
  dim3 grid(mt * nt * ksplit), blk(256);
  if (act == 1)      gemm_bf<1><<<grid, blk, 0, s>>>(A, Bt, bias, res, C, Cbf, Cpart, M, N, K, scale, mt, nt, ksplit);
  else if (act == 2) gemm_bf<2><<<grid, blk, 0, s>>>(A, Bt, bias, res, C, Cbf, Cpart, M, N, K, scale, mt, nt, ksplit);
  else               gemm_bf<0><<<grid, blk, 0, s>>>(A, Bt, bias, res, C, Cbf, Cpart, M, N, K, scale, mt, nt, ksplit);
}

static void conv_launch(const float* W, short* Wt, int K, int N, hipStream_t s)
{
  int nt = N >> 6, kt = K >> 6;
  convT<<<dim3(nt * kt), dim3(256), 0, s>>>(W, Wt, K, N, nt);
}

static void thin_launch(int act, const float* A, const float* W, const float* bias,
                        float* C, float* part, int K, int N, hipStream_t s)
{
  int nblk = N >> 8, splits = 64;
  thin1<<<dim3(nblk * splits), dim3(256), 0, s>>>(A, W, part, K, N, nblk, splits);
  if (act == 2) thin2<2><<<dim3(nblk), dim3(256), 0, s>>>(part, bias, C, N, splits);
  else          thin2<0><<<dim3(nblk), dim3(256), 0, s>>>(part, bias, C, N, splits);
}

extern "C" void kernel_launch(void* const* d_in, const int* in_sizes, int n_in,
                              void* d_out, int out_size, void* d_ws, size_t ws_size,
                              hipStream_t stream)
{
  (void)in_sizes; (void)n_in; (void)out_size; (void)ws_size;
  const float* l2r      = (const float*)d_in[0];
  const float* r2l      = (const float*)d_in[1];
  const float* temb     = (const float*)d_in[2];
  const float* ln_l2r_s = (const float*)d_in[3];
  const float* ln_l2r_b = (const float*)d_in[4];
  const float* ln_r2l_s = (const float*)d_in[5];
  const float* ln_r2l_b = (const float*)d_in[6];
  const float* Wq = (const float*)d_in[7];
  const float* bq = (const float*)d_in[8];
  const float* Wk = (const float*)d_in[9];
  const float* bk = (const float*)d_in[10];
  const float* Wv = (const float*)d_in[11];
  const float* bv = (const float*)d_in[12];
  const float* Wo = (const float*)d_in[13];
  const float* bo = (const float*)d_in[14];
  const float* ff_ln_s = (const float*)d_in[15];
  const float* ff_ln_b = (const float*)d_in[16];
  const float* ff_w1 = (const float*)d_in[17];
  const float* ff_b1 = (const float*)d_in[18];
  const float* ff_w2 = (const float*)d_in[19];
  const float* ff_b2 = (const float*)d_in[20];
  const float* tm_w1 = (const float*)d_in[21];
  const float* tm_b1 = (const float*)d_in[22];
  const float* tm_w2 = (const float*)d_in[23];
  const float* tm_b2 = (const float*)d_in[24];
  const float* film_w = (const float*)d_in[25];
  const float* film_b = (const float*)d_in[26];
  const float* r_w1 = (const float*)d_in[27];
  const float* r_b1 = (const float*)d_in[28];
  const float* r_w2 = (const float*)d_in[29];
  const float* r_b2 = (const float*)d_in[30];
  const float* r_ln_s = (const float*)d_in[31];
  const float* r_ln_b = (const float*)d_in[32];
  const float* out_w = (const float*)d_in[33];
  const float* out_b = (const float*)d_in[34];

  uint8_t* base = (uint8_t*)d_ws;
  short* qin_bf  = (short*)(base + 0);
  short* alle_bf = (short*)(base + 3145728);
  short* qb      = (short*)(base + 9440256);
  short* kvbuf   = (short*)(base + 12585984);
  short* attn_bf = (short*)(base + 25175040);
  float* inputs  = (float*)(base + 28320768);
  float* xbuf    = (float*)(base + 34612224);
  short* xn_bf   = (short*)(base + 40903680);
  short* big_bf  = (short*)(base + 44049408);   // 12,582,912
  float* x2f     = (float*)(base + 56632320);
  short* x2bf    = (short*)(base + 62923776);
  float* x3f     = (float*)(base + 72360960);
  short* x3bf    = (short*)(base + 78652416);
  short* x4bf    = (short*)(base + 81798144);
  short* wslot   = (short*)(base + 84943872);
  uint8_t* sm    = base + 89662464;
  float* t1    = (float*)sm;                    // 24,576
  float* tb    = (float*)(sm + 24576);          // 24,576
  float* f0    = (float*)(sm + 49152);          // 12,288
  float* f1    = (float*)(sm + 61440);          // 12,288
  float* kvbia = (float*)(sm + 73728);          // 6,144
  // thin split-K partials alias big_bf (dead during t-path)
  float* part2 = (float*)(base + 44049408);
  // split-K(4) partials: 4 x 6,291,456 = 25,165,824 B at base+0 (dead after attention; < attn_bf @25,175,040)
  float* partK = (float*)(base + 0);
  short* outwT = (short*)(base + 0);            // 49.15 MB, used only at the end

  const float qscale = 0.1020620726159658f;  // 1/sqrt(96)
  dim3 blk(256);

  // t-path (independent, f32)
  thin_launch(2, temb, tm_w1, tm_b1, t1, part2, 768, 3072, stream);
  thin_launch(0, t1, tm_w2, tm_b2, tb, part2, 3072, 3072, stream);
  film1<<<dim3(12 * 64), blk, 0, stream>>>(tb, film_w, part2);
  film2<<<dim3(12), blk, 0, stream>>>(part2, film_b, f0, f1);

  prep_kernel<<<2050, blk, 0, stream>>>(l2r, r2l, temb, ln_l2r_s, ln_l2r_b, ln_r2l_s, ln_r2l_b,
                                        inputs, qin_bf, alle_bf);

  convT4<<<dim3(577), blk, 0, stream>>>(Wq, Wk, Wv, Wo, bk, bv, wslot, kvbia);

  gemm_launch(0, qin_bf, wslot, bq, nullptr, nullptr, qb, nullptr, 2048, 768, 768, qscale, 1, stream);
  gemm_launch(0, alle_bf, wslot + (size_t)768 * 768, kvbia, nullptr, nullptr, kvbuf, nullptr, 4098, 1536, 768, 1.f, 1, stream);

  attn_kernel<<<256, blk, 0, stream>>>(qb, kvbuf, attn_bf);

  gemm_launch(0, attn_bf, wslot + (size_t)3 * 768 * 768, bo, inputs, xbuf, nullptr, nullptr, 2048, 768, 768, 1.f, 1, stream);
  ln_kernel<<<2048, blk, 0, stream>>>(xbuf, ff_ln_s, ff_ln_b, xn_bf);

  conv_launch(ff_w1, wslot, 768, 3072, stream);
  gemm_launch(1, xn_bf, wslot, ff_b1, nullptr, nullptr, big_bf, nullptr, 2048, 3072, 768, 1.f, 1, stream);
  conv_launch(ff_w2, wslot, 3072, 768, stream);
  gemm_launch(0, big_bf, wslot, nullptr, nullptr, nullptr, nullptr, partK, 2048, 768, 3072, 1.f, 4, stream);
  combine_kernel<<<2048, blk, 0, stream>>>(partK, ff_b2, xbuf, x2f, x2bf);

  // residual block 0
  conv_launch(r_w1, wslot, 768, 3072, stream);
  gemm_launch(2, x2bf, wslot, r_b1, nullptr, nullptr, big_bf, nullptr, 2048, 3072, 768, 1.f, 1, stream);
  conv_launch(r_w2, wslot, 3072, 768, stream);
  gemm_launch(0, big_bf, wslot, nullptr, nullptr, nullptr, nullptr, partK, 2048, 768, 3072, 1.f, 4, stream);
  ln_comb<<<2048, blk, 0, stream>>>(partK, r_b2, x2f, r_ln_s, r_ln_b, f0, x3f, x3bf);

  // residual block 1
  conv_launch(r_w1 + (size_t)768 * 3072, wslot, 768, 3072, stream);
  gemm_launch(2, x3bf, wslot, r_b1 + 3072, nullptr, nullptr, big_bf, nullptr, 2048, 3072, 768, 1.f, 1, stream);
  conv_launch(r_w2 + (size_t)3072 * 768, wslot, 3072, 768, stream);
  gemm_launch(0, big_bf, wslot, nullptr, nullptr, nullptr, nullptr, partK, 2048, 768, 3072, 1.f, 4, stream);
  ln_comb<<<2048, blk, 0, stream>>>(partK, r_b2 + 768, x3f, r_ln_s + 768, r_ln_b + 768, f1, nullptr, x4bf);

  // vocab projection: convert out_w, then 256^2 dbuf GEMM
  conv_launch(out_w, outwT, 768, 32000, stream);
  gemm256<<<dim3(8 * 125), dim3(512), 0, stream>>>(x4bf, outwT, out_b, (float*)d_out,
                                                   2048, 32000, 768, 8);
}